// Round 26
// baseline (802.574 us; speedup 1.0000x reference)
//
#include <hip/hip_runtime.h>
#include <hip/hip_bf16.h>

#define TPB 256
#define TPA 512

constexpr int Bx = 8, Cc = 64, Nn = 207, Tin = 54, Kb = 8;
constexpr int LP = 52, NP = Nn * LP;     // time padded 50->52, flattened node*time positions
constexpr int NPa = 10816;               // NP rounded up to 169*64 for MFMA tiles
constexpr int L50 = 50, Tout = 48;
constexpr int Ee = 512, Pn = 12;
constexpr float EPSF = 1e-5f;
constexpr int SRDF = 516;                // padded row stride for 512-wide f32 LDS rows (2-way bank pattern)

// ---------------- workspace layout (floats) ----------------
constexpr size_t O_RESID = 0;                                   // [B][64][207][54]
constexpr size_t O_LNTM  = O_RESID + (size_t)Bx*Cc*Nn*Tin;
constexpr size_t O_LNTR  = O_LNTM  + (size_t)Bx*Cc*Nn;
constexpr size_t O_LNSM  = O_LNTR  + (size_t)Bx*Cc*Nn;
constexpr size_t O_LNSR  = O_LNSM  + (size_t)Bx*Cc*Tin;
constexpr size_t O_XCAT  = O_LNSR  + (size_t)Bx*Cc*Tin;         // RA bf16 x3 slots (16.53M of 17.17M floats)
constexpr size_t O_RB    = O_XCAT  + (size_t)Bx*192*Nn*Tin;     // RB0,RB1 bf16 slots (fills region exactly)
constexpr size_t O_H     = O_RB    + (size_t)Bx*128*NP;         // HT bf16 [Bx][NPa][64]
constexpr size_t O_GACC  = O_H     + (size_t)Bx*64*NP;          // S1 bf16 x3 slots; RB2 bf16 overlays dead S1 after gcs128
constexpr size_t O_GG    = O_GACC  + (size_t)Bx*128*Nn*Tout;    // Y [B][64][207][48] (GG eliminated)
constexpr size_t O_XE    = O_GG    + (size_t)Bx*64*Nn*Tout;     // XE [B][207][12][512] (written by mlp_all)
constexpr size_t O_WTT   = O_XE    + (size_t)Bx*Nn*Pn*Ee;       // (unused) 128*192*3
constexpr size_t O_WTM   = O_WTT   + (size_t)128*192*3;         // ushort[3*8*12*512] W_mlp frag bf16
constexpr size_t O_BNST  = O_WTM   + (size_t)128*384*3;         // 128
constexpr size_t O_WTB   = O_BNST + 128;                        // ushort[8*18*512] time-conv bf16 frag weights
constexpr size_t O_ADJT  = O_WTB  + (size_t)128*576/2;          // ushort[3][13*7*512] adj frag bf16
constexpr size_t O_HT    = O_H;                                 // ushort[Bx][NPa][64] in dead H region
// weight frag buffers in high free region (after ADJT):
constexpr size_t O_WQ1B  = O_ADJT + (size_t)3*13*7*512/2;       // ushort[24*4*2*512]
constexpr size_t O_WV1B  = O_WQ1B + (size_t)24*4*2*512/2;
constexpr size_t O_WQ2B  = O_WV1B + (size_t)24*4*2*512/2;       // ushort[24*8*2*512]
constexpr size_t O_WV2B  = O_WQ2B + (size_t)24*8*2*512/2;
constexpr size_t O_WQT   = O_WV2B + (size_t)24*8*2*512/2;       // ushort[4*2*512]
constexpr size_t O_WKT   = O_WQT  + 2048;
constexpr size_t O_WVT   = O_WKT  + 2048;
constexpr size_t O_WFCT  = O_WVT  + 2048;                       // ushort[32*16*512]
constexpr size_t O_WF1T  = O_WFCT + 131072;                     // ushort[16*16*512]
constexpr size_t O_WF2T  = O_WF1T + 65536;                      // ushort[32*8*512]; ends ~65.99M < 67.1M

#define FMA4(acc, sA_, vB_) { (acc).x += (sA_)*(vB_).x; (acc).y += (sA_)*(vB_).y; (acc).z += (sA_)*(vB_).z; (acc).w += (sA_)*(vB_).w; }

typedef __attribute__((ext_vector_type(8))) short bf16x8;
typedef __attribute__((ext_vector_type(4))) float f32x4;

__device__ __forceinline__ float sigm(float x){ return 1.0f/(1.0f+__expf(-x)); }
__device__ __forceinline__ ushort f2bf(float x){ __hip_bfloat16 h = __float2bfloat16(x); return *(ushort*)&h; }

// ---------------- residual = W_conv1 @ x + b, fused lnT stats ----------------
__global__ __launch_bounds__(TPB) void k_residual(const float* __restrict__ x, const float* __restrict__ W,
                                                  const float* __restrict__ bias, float* __restrict__ out,
                                                  float* __restrict__ lnm, float* __restrict__ lnr){
  int n = blockIdx.x, b = blockIdx.y;
  __shared__ __align__(16) float sX[Cc][Tin];
  __shared__ __align__(16) float sW[Cc*Cc];
  __shared__ __align__(16) float sO[Cc][Tin];
  int tid = threadIdx.x;
  for(int i=tid;i<Cc*Tin;i+=TPB){ int c=i/Tin, l=i%Tin; sX[c][l] = x[((size_t)(b*Cc+c)*Nn+n)*Tin+l]; }
  for(int i=tid;i<Cc*Cc;i+=TPB) sW[i]=W[i];
  __syncthreads();
  for(int i=tid;i<Cc*Tin;i+=TPB){
    int o=i/Tin, l=i%Tin; float acc=bias[o];
    #pragma unroll 8
    for(int c=0;c<Cc;c++) acc += sW[o*Cc+c]*sX[c][l];
    out[((size_t)(b*Cc+o)*Nn+n)*Tin+l]=acc;
    sO[o][l]=acc;
  }
  __syncthreads();
  if(tid < Cc){
    float s=0.f,s2=0.f;
    for(int l=0;l<Tin;l++){ float v=sO[tid][l]; s+=v; s2+=v*v; }
    float m=s*(1.f/Tin); float var=s2*(1.f/Tin)-m*m;
    int row = (b*Cc+tid)*Nn + n;
    lnm[row]=m; lnr[row]=rsqrtf(fmaxf(var,0.f)+EPSF);
  }
}

// ---------------- lnS stats ----------------
__global__ __launch_bounds__(TPB) void k_lnS(const float* __restrict__ r, float* __restrict__ mean, float* __restrict__ rstd){
  int row = blockIdx.x*TPB + threadIdx.x;       // (b*Cc+c)*Tin + l
  if(row >= Bx*Cc*Tin) return;
  int l = row % Tin; int bc = row / Tin;
  const float* p = r + (size_t)bc*Nn*Tin + l;
  float s=0.f,s2=0.f;
  for(int n=0;n<Nn;n++){ float v=p[(size_t)n*Tin]; s+=v; s2+=v*v; }
  float m=s*(1.f/Nn); float var=s2*(1.f/Nn)-m*m;
  mean[row]=m; rstd[row]=rsqrtf(fmaxf(var,0.f)+EPSF);
}

// ---------------- merged fragment-order weight converter (13 jobs: generic/timeconv/mlp) ----------------
struct WJob { const float* W; ushort* F; int K, N, KS, NT, sStride, total, type; };
struct WJobs { WJob j[13]; };

__global__ __launch_bounds__(TPB) void k_wfrag_all(WJobs jobs){
  int gi = blockIdx.x*TPB + threadIdx.x;
  for(int seg=0; seg<13; seg++){
    const WJob J = jobs.j[seg];
    if(gi < J.total){
      int i = gi;
      int j = i & 7; int lane = (i>>3) & 63;
      int t = i >> 9;
      int r15 = lane & 15, hi = lane >> 4;
      float v;
      if(J.type == 0){
        int ks = t % J.KS; int r = t / J.KS; int colTile = r % J.NT; int s = r / J.NT;
        int k = ks*32 + hi*8 + j, col = colTile*16 + r15;
        v = (k < J.K && col < J.N) ? J.W[(size_t)s*J.sStride + (size_t)k*J.N + col] : 0.f;
      } else if(J.type == 1){
        int ks = t % 18; int colTile = t / 18;
        int k = ks*32 + hi*8 + j, o = colTile*16 + r15;
        int kt = k/192, ci = k - kt*192;
        v = J.W[(size_t)(o*192+ci)*3 + kt];
      } else {
        int ks = t % 12; int r = t / 12; int colTile = r & 7; int layer = r >> 3;
        int k = ks*32 + hi*8 + j;
        int kt = k >> 7, ci = k & 127;
        int o = colTile*16 + r15;
        v = J.W[(size_t)(o*384 + layer*128 + ci)*3 + kt];
      }
      J.F[i] = f2bf(v);
      return;
    }
    gi -= J.total;
  }
}

// ---------------- fused xcat+dilated time conv (dil=2) + GLU via MFMA -> HT bf16 [b][p][64] ----------------
__global__ __launch_bounds__(TPB) void k_timeconv_mfma(const float* __restrict__ resid,
    const float* __restrict__ tm, const float* __restrict__ tr,
    const float* __restrict__ sm, const float* __restrict__ sr,
    const float* __restrict__ gT, const float* __restrict__ bT,
    const float* __restrict__ gS, const float* __restrict__ bS,
    const ushort* __restrict__ WF, const float* __restrict__ bias, ushort* __restrict__ HT){
  int n = blockIdx.x, b = blockIdx.y;
  constexpr int XS = 200;
  __shared__ __align__(16) ushort sXT[68*XS];
  int tid = threadIdx.x;
  for(int i=tid; i<14*XS; i+=TPB) sXT[54*XS + i] = 0;
  float gSn = gS[n], bSn = bS[n];
  for(int i=tid; i<64*54; i+=TPB){
    int cm = i/54, l = i%54;
    int rowT = (b*Cc+cm)*Nn + n;
    float r = resid[(size_t)rowT*Tin + l];
    float v1 = (r - tm[rowT]) * tr[rowT] * gT[l] + bT[l];
    int rowS = (b*Cc+cm)*Tin + l;
    float v2 = (r - sm[rowS]) * sr[rowS] * gSn + bSn;
    sXT[l*XS + cm]        = f2bf(r);
    sXT[l*XS + 64 + cm]   = f2bf(v1);
    sXT[l*XS + 128 + cm]  = f2bf(v2);
  }
  __syncthreads();
  int lane = tid & 63, w = tid >> 6;
  int r15 = lane & 15, hi = lane >> 4;
  float b0 = bias[w*16 + r15], b1 = bias[w*16 + 64 + r15];
  f32x4 acc0[4], acc1[4];
  #pragma unroll
  for(int tt=0;tt<4;tt++){
    acc0[tt][0]=b0; acc0[tt][1]=b0; acc0[tt][2]=b0; acc0[tt][3]=b0;
    acc1[tt][0]=b1; acc1[tt][1]=b1; acc1[tt][2]=b1; acc1[tt][3]=b1;
  }
  const ushort* wp0 = WF + ((size_t)w*18)*512 + lane*8;
  const ushort* wp1 = WF + ((size_t)(w+4)*18)*512 + lane*8;
  #pragma unroll 2
  for(int ks=0; ks<18; ks++){
    int k0 = ks*32 + hi*8;
    int kt = k0/192, ci0 = k0 - kt*192;
    bf16x8 bw0 = *(const bf16x8*)&wp0[(size_t)ks*512];
    bf16x8 bw1 = *(const bf16x8*)&wp1[(size_t)ks*512];
    #pragma unroll
    for(int tt=0;tt<4;tt++){
      bf16x8 ax = *(const bf16x8*)&sXT[(tt*16 + r15 + 2*kt)*XS + ci0];
      acc0[tt] = __builtin_amdgcn_mfma_f32_16x16x32_bf16(ax, bw0, acc0[tt], 0,0,0);
      acc1[tt] = __builtin_amdgcn_mfma_f32_16x16x32_bf16(ax, bw1, acc1[tt], 0,0,0);
    }
  }
  ushort* htp = HT + ((size_t)b*NPa + (size_t)n*LP)*64;
  int c = w*16 + r15;
  #pragma unroll
  for(int tt=0;tt<4;tt++){
    int t0 = tt*16 + hi*4;
    #pragma unroll
    for(int i=0;i<4;i++){
      int t = t0 + i;
      if(t < L50) htp[(size_t)t*64 + c] = f2bf(tanhf(acc0[tt][i])*sigm(acc1[tt][i]));
    }
  }
  if(tid < 128){ int cz = tid >> 1, tz = 50 + (tid & 1); htp[(size_t)tz*64 + cz] = 0; }
}

// ---------------- zero HT padding rows p in [NP, NPa) ----------------
__global__ __launch_bounds__(TPB) void k_htpad(ushort* __restrict__ HT){
  int i = blockIdx.x*TPB + threadIdx.x;
  int per = (NPa-NP)*8;                           // 8 uint4 per row of 64 ushorts
  if(i >= Bx*per) return;
  int b = i / per, r = i % per;
  uint4 z; z.x=0;z.y=0;z.z=0;z.w=0;
  *(uint4*)&HT[((size_t)b*NPa + NP)*64 + (size_t)r*8] = z;
}

// ---------------- gated multi-basis GCN einsum via MFMA; all 3 layers in one dispatch ----------------
// TR=0: input XT bf16 [b][NPa][64] shared across i; TR=1: per-i input bf16 [b][64][NP] at XT+i*inSlot
template<int D, int TR>
__global__ __launch_bounds__(TPB) void k_gcs_mfma(const ushort* __restrict__ XT,
    const ushort* __restrict__ wqF, const ushort* __restrict__ wvF,
    ushort* __restrict__ S, size_t inSlot, size_t outSlot){
  constexpr int Dt = D/16;
  constexpr int nY = D/64;
  constexpr size_t WSTR = (size_t)Kb*Dt*2*512;
  int p0 = blockIdx.x*64;
  int b = blockIdx.z;
  int iy = blockIdx.y / nY;          // GCN layer index i in [0,3)
  int dblk = blockIdx.y % nY;
  int tid = threadIdx.x;
  int lane = tid & 63, w = tid >> 6;
  int d0 = dblk*64 + (w<<4);
  int dTile = dblk*4 + w;
  const ushort* wqB = wqF + iy*WSTR;
  const ushort* wvB = wvF + iy*WSTR;
  ushort* Sb = S + iy*outSlot;
  __shared__ __align__(16) ushort sX[64*64];
  if constexpr(TR){
    const ushort* Xp = XT + iy*inSlot;
    __shared__ __align__(16) ushort sT2[64*66];
    for(int i=tid;i<4096;i+=TPB){ int c=i>>6, col=i&63; int p=p0+col;
      sT2[c*66+col] = (p<NP) ? Xp[((size_t)(b*64+c))*NP + p] : (ushort)0; }
    __syncthreads();
    for(int i=tid;i<512;i+=TPB){
      int row=i>>3, c8=(i&7)<<3;
      ushort u[8];
      #pragma unroll
      for(int j=0;j<8;j++) u[j] = sT2[(c8+j)*66 + row];
      *(uint4*)&sX[row*64 + (c8 ^ ((row&7)<<3))] = *(uint4*)u;
    }
  } else {
    for(int i=tid;i<512;i+=TPB){
      int row=i>>3, c8=(i&7)<<3;
      uint4 v = *(const uint4*)&XT[((size_t)b*NPa + p0 + row)*64 + c8];
      *(uint4*)&sX[row*64 + (c8 ^ ((row&7)<<3))] = v;
    }
  }
  __syncthreads();
  int r15 = lane & 15, hi = lane >> 4;
  bf16x8 bf[4][2];
  #pragma unroll
  for(int pt=0;pt<4;pt++){
    int row = pt*16 + r15;
    int sw = (row&7)<<3;
    int cu0 = hi*8;
    bf[pt][0] = *(const bf16x8*)&sX[row*64 + (cu0 ^ sw)];
    bf[pt][1] = *(const bf16x8*)&sX[row*64 + ((cu0+32) ^ sw)];
  }
  f32x4 acc[4];
  #pragma unroll
  for(int pt=0;pt<4;pt++){ acc[pt][0]=0.f; acc[pt][1]=0.f; acc[pt][2]=0.f; acc[pt][3]=0.f; }
  const ushort* wqp = wqB + ((size_t)dTile*2)*512 + lane*8;
  const ushort* wvp = wvB + ((size_t)dTile*2)*512 + lane*8;
  for(int k=0;k<Kb;k++){
    bf16x8 aq0 = *(const bf16x8*)&wqp[0];
    bf16x8 aq1 = *(const bf16x8*)&wqp[512];
    bf16x8 av0 = *(const bf16x8*)&wvp[0];
    bf16x8 av1 = *(const bf16x8*)&wvp[512];
    wqp += (size_t)Dt*2*512; wvp += (size_t)Dt*2*512;
    #pragma unroll
    for(int pt=0;pt<4;pt++){
      f32x4 q; q[0]=0.f;q[1]=0.f;q[2]=0.f;q[3]=0.f;
      f32x4 v; v[0]=0.f;v[1]=0.f;v[2]=0.f;v[3]=0.f;
      q = __builtin_amdgcn_mfma_f32_16x16x32_bf16(aq0, bf[pt][0], q, 0,0,0);
      q = __builtin_amdgcn_mfma_f32_16x16x32_bf16(aq1, bf[pt][1], q, 0,0,0);
      v = __builtin_amdgcn_mfma_f32_16x16x32_bf16(av0, bf[pt][0], v, 0,0,0);
      v = __builtin_amdgcn_mfma_f32_16x16x32_bf16(av1, bf[pt][1], v, 0,0,0);
      #pragma unroll
      for(int i=0;i<4;i++) acc[pt][i] += v[i]*sigm(q[i]);
    }
  }
  #pragma unroll
  for(int pt=0;pt<4;pt++){
    int p = p0 + pt*16 + r15;
    if(p < NP){
      #pragma unroll
      for(int i=0;i<4;i++){
        int d = d0 + hi*4 + i;
        Sb[((size_t)b*D + d)*NP + p] = f2bf(acc[pt][i]);
      }
    }
  }
}

// ---------------- adjacency aggregation via MFMA; all 3 layers in one dispatch ----------------
template<int RELU>
__global__ __launch_bounds__(TPB) void k_agg_mfma(const ushort* __restrict__ S, const ushort* __restrict__ adjF,
                                                  const float* __restrict__ bias,
                                                  ushort* __restrict__ O0, ushort* __restrict__ O1, ushort* __restrict__ O2,
                                                  int D, size_t inSlot){
  int d = blockIdx.x;
  int by = blockIdx.y;
  int b = by / 3, li = by % 3;          // li = GCN layer index
  int bd = b*D + d;
  const ushort* adjL = adjF + (size_t)li*13*7*512;
  constexpr int SST = 232;
  __shared__ __align__(16) ushort sB[64*SST];
  int tid = threadIdx.x;
  for(int i=tid*8; i<64*SST; i+=TPB*8){ uint4 z; z.x=0;z.y=0;z.z=0;z.w=0; *(uint4*)&sB[i]=z; }
  __syncthreads();
  const ushort* Sp = S + li*inSlot + (size_t)bd*NP;
  for(int i=tid; i<NP; i+=TPB){
    int nn = i/52, l = i - nn*52;
    sB[l*SST + nn] = Sp[i];
  }
  __syncthreads();
  int lane = tid & 63, w = tid >> 6;
  int r15 = lane & 15, hi = lane >> 4;
  float bb = bias[li*D + d];
  ushort* Ob = (li==0) ? O0 : (li==1 ? O1 : O2);
  ushort* Op = Ob + (size_t)bd*NP;
  for(int k2t = w; k2t < 13; k2t += 4){
    f32x4 acc[4];
    #pragma unroll
    for(int lt=0;lt<4;lt++){ acc[lt][0]=0;acc[lt][1]=0;acc[lt][2]=0;acc[lt][3]=0; }
    #pragma unroll
    for(int ks=0; ks<7; ks++){
      bf16x8 a = *(const bf16x8*)&adjL[((size_t)(k2t*7 + ks))*512 + lane*8];
      #pragma unroll
      for(int lt=0;lt<4;lt++){
        bf16x8 bfr = *(const bf16x8*)&sB[(lt*16+r15)*SST + ks*32 + hi*8];
        acc[lt] = __builtin_amdgcn_mfma_f32_16x16x32_bf16(a, bfr, acc[lt], 0,0,0);
      }
    }
    #pragma unroll
    for(int lt=0;lt<4;lt++){
      #pragma unroll
      for(int i2=0;i2<4;i2++){
        int k2 = k2t*16 + hi*4 + i2;
        int l  = lt*16 + r15;
        if(k2 < Nn && l < LP){
          float v = acc[lt][i2] + bb;
          if(RELU) v = fmaxf(v, 0.f);
          Op[(size_t)k2*LP + l] = f2bf(v);
        }
      }
    }
  }
}

// ---------------- fused MLP conv (3 layers) + patch-scramble + emb -> XE directly ----------------
__global__ __launch_bounds__(TPB) void k_mlp_all(const ushort* __restrict__ RB0, const ushort* __restrict__ RB1,
                                                 const ushort* __restrict__ RB2, const ushort* __restrict__ WF,
                                                 const float* __restrict__ bm, const float* __restrict__ emb,
                                                 float* __restrict__ xe){
  int n = blockIdx.x, b = blockIdx.y;
  constexpr int CS = 136;
  __shared__ __align__(16) ushort sLT[3*52*CS];
  int tid = threadIdx.x;
  {
    const ushort* Rp = RB0;
    for(int i=tid;i<6656;i+=TPB){ int c=i/52, l=i%52; sLT[0*52*CS + l*CS + c] = Rp[(((size_t)b*128+c)*Nn + n)*LP + l]; }
    Rp = RB1;
    for(int i=tid;i<6656;i+=TPB){ int c=i/52, l=i%52; sLT[1*52*CS + l*CS + c] = Rp[(((size_t)b*128+c)*Nn + n)*LP + l]; }
    Rp = RB2;
    for(int i=tid;i<6656;i+=TPB){ int c=i/52, l=i%52; sLT[2*52*CS + l*CS + c] = Rp[(((size_t)b*128+c)*Nn + n)*LP + l]; }
  }
  __syncthreads();
  int lane = tid & 63, w = tid >> 6;
  int r15 = lane & 15, hi = lane >> 4;
  f32x4 acc0[3], acc1[3];
  #pragma unroll
  for(int tt=0;tt<3;tt++){
    acc0[tt][0]=0;acc0[tt][1]=0;acc0[tt][2]=0;acc0[tt][3]=0;
    acc1[tt][0]=0;acc1[tt][1]=0;acc1[tt][2]=0;acc1[tt][3]=0;
  }
  #pragma unroll
  for(int layer=0; layer<3; layer++){
    const ushort* wp0 = WF + ((size_t)(layer*8 + w)*12)*512 + lane*8;
    const ushort* wp1 = WF + ((size_t)(layer*8 + w+4)*12)*512 + lane*8;
    const ushort* sL = &sLT[layer*52*CS];
    #pragma unroll 3
    for(int ks=0; ks<12; ks++){
      int kt = ks>>2, ci0 = (ks&3)*32 + hi*8;
      bf16x8 bw0 = *(const bf16x8*)&wp0[(size_t)ks*512];
      bf16x8 bw1 = *(const bf16x8*)&wp1[(size_t)ks*512];
      #pragma unroll
      for(int tt=0;tt<3;tt++){
        bf16x8 ax = *(const bf16x8*)&sL[(tt*16 + r15 + kt)*CS + ci0];
        acc0[tt] = __builtin_amdgcn_mfma_f32_16x16x32_bf16(ax, bw0, acc0[tt], 0,0,0);
        acc1[tt] = __builtin_amdgcn_mfma_f32_16x16x32_bf16(ax, bw1, acc1[tt], 0,0,0);
      }
    }
  }
  int o = w*16 + r15;
  float b0 = bm[o], b1 = bm[o+64];
  float* xeb = xe + (size_t)b*1271808;
  int off0 = o*19872 + n*96;
  #pragma unroll
  for(int tt=0;tt<3;tt++){
    #pragma unroll
    for(int i2=0;i2<4;i2++){
      int tq = tt*16 + hi*4 + i2;
      float v = tanhf(acc0[tt][i2] + b0)*sigm(acc1[tt][i2] + b1);
      int p1 = tq>>2, j1 = tq&3;
      int offa = off0 + p1*8 + j1;
      xeb[offa] = v + emb[(size_t)((offa>>9)%12)*Ee + (offa&511)];
      if(tq >= 4){
        int offb = off0 + (p1-1)*8 + j1 + 4;
        xeb[offb] = v + emb[(size_t)((offb>>9)%12)*Ee + (offb&511)];
      }
    }
  }
  // pad entries r2 in [92,96): t>=48 -> emb only (one per thread; 64 c x 4)
  {
    int o2 = tid >> 2, r2 = 92 + (tid & 3);
    int offp = o2*19872 + n*96 + r2;
    xeb[offp] = emb[(size_t)((offp>>9)%12)*Ee + (offp&511)];
  }
}

// ---------------- per-row LN helper (rows of 512, stride SRDF, in LDS); NW waves ----------------
template<int NW>
__device__ __forceinline__ void ln_rows(float* buf, const float* __restrict__ g, const float* __restrict__ be, int tid){
  int lane = tid & 63, wv = tid >> 6;
  for(int r = wv; r < 12; r += NW){
    float s=0.f, s2=0.f;
    #pragma unroll
    for(int j=0;j<8;j++){ float v = buf[r*SRDF + j*64 + lane]; s+=v; s2+=v*v; }
    #pragma unroll
    for(int off=32; off; off>>=1){ s += __shfl_xor(s,off); s2 += __shfl_xor(s2,off); }
    float m = s*(1.f/512.f);
    float rstd = rsqrtf(fmaxf(s2*(1.f/512.f)-m*m, 0.f)+EPSF);
    #pragma unroll
    for(int j=0;j<8;j++){ int e = j*64+lane; float v = buf[r*SRDF+e];
      buf[r*SRDF+e] = (v-m)*rstd*g[e] + be[e]; }
  }
}

// ---------------- fused per-(b,n) transformer, MFMA GEMM phases; 512 threads (8 waves) ----------------
__global__ __launch_bounds__(TPA,2) void k_attn(
    const float* __restrict__ xe, const float* __restrict__ resid,
    const ushort* __restrict__ WqF, const float* __restrict__ bq,
    const ushort* __restrict__ WkF, const float* __restrict__ bk,
    const ushort* __restrict__ WvF, const float* __restrict__ bv,
    const ushort* __restrict__ WfcF, const float* __restrict__ bfc,
    const float* __restrict__ g1, const float* __restrict__ b1n,
    const float* __restrict__ g2, const float* __restrict__ b2n,
    const ushort* __restrict__ Wff1F, const float* __restrict__ bff1,
    const ushort* __restrict__ Wff2F, const float* __restrict__ bff2,
    const float* __restrict__ Wrp, const float* __restrict__ brp,
    float* __restrict__ y)
{
  int n = blockIdx.x, b = blockIdx.y;
  __shared__ __align__(16) ushort SbX[16*512];
  __shared__ __align__(16) ushort Mb[16*256];
  __shared__ __align__(16) float U0[12*SRDF];
  __shared__ __align__(16) float U1[12*SRDF];
  __shared__ __align__(16) float sS[1160];
  int tid = threadIdx.x;
  int lane = tid & 63, w = tid >> 6;          // w in [0,8)
  int r15 = lane & 15, hi = lane >> 4;
  const float* __restrict__ xeg = xe + ((size_t)b*Nn + n)*6144;

  for(int i=tid;i<1024;i+=TPA){
    int r = i>>6, ch = i&63;
    ushort u[8];
    if(r<12){
      const float* s = &xeg[r*512 + ch*8];
      #pragma unroll
      for(int j=0;j<8;j++) u[j] = f2bf(s[j]);
    } else {
      #pragma unroll
      for(int j=0;j<8;j++) u[j] = 0;
    }
    *(uint4*)&SbX[r*512 + ((ch ^ (r&7))<<3)] = *(uint4*)u;
  }
  for(int i=tid;i<128;i+=TPA){
    int r = 12 + (i>>5), ch = i&31;
    uint4 z; z.x=0;z.y=0;z.z=0;z.w=0;
    *(uint4*)&Mb[r*256 + ch*8] = z;
  }
  __syncthreads();

  // QKV: one head per wave
  f32x4 vfrag[4];
  {
    int head = w;
    bf16x8 a0, a1;
    { int ch0 = head*8 + hi, ch1 = head*8 + 4 + hi;
      a0 = *(const bf16x8*)&SbX[r15*512 + ((ch0 ^ (r15&7))<<3)];
      a1 = *(const bf16x8*)&SbX[r15*512 + ((ch1 ^ (r15&7))<<3)]; }
    #pragma unroll
    for(int nt=0;nt<4;nt++){
      int col = nt*16 + r15;
      float bb = bq[col];
      f32x4 acc; acc[0]=bb;acc[1]=bb;acc[2]=bb;acc[3]=bb;
      acc = __builtin_amdgcn_mfma_f32_16x16x32_bf16(a0, *(const bf16x8*)&WqF[(size_t)(nt*2+0)*512 + lane*8], acc, 0,0,0);
      acc = __builtin_amdgcn_mfma_f32_16x16x32_bf16(a1, *(const bf16x8*)&WqF[(size_t)(nt*2+1)*512 + lane*8], acc, 0,0,0);
      #pragma unroll
      for(int i2=0;i2<4;i2++){ int p = hi*4+i2; if(p<12) U0[p*SRDF + head*64 + col] = acc[i2]; }
    }
    #pragma unroll
    for(int nt=0;nt<4;nt++){
      int col = nt*16 + r15;
      float bb = bk[col];
      f32x4 acc; acc[0]=bb;acc[1]=bb;acc[2]=bb;acc[3]=bb;
      acc = __builtin_amdgcn_mfma_f32_16x16x32_bf16(a0, *(const bf16x8*)&WkF[(size_t)(nt*2+0)*512 + lane*8], acc, 0,0,0);
      acc = __builtin_amdgcn_mfma_f32_16x16x32_bf16(a1, *(const bf16x8*)&WkF[(size_t)(nt*2+1)*512 + lane*8], acc, 0,0,0);
      #pragma unroll
      for(int i2=0;i2<4;i2++){ int p = hi*4+i2; if(p<12) U1[p*SRDF + head*64 + col] = acc[i2]; }
    }
    #pragma unroll
    for(int nt=0;nt<4;nt++){
      int col = nt*16 + r15;
      float bb = bv[col];
      f32x4 acc; acc[0]=bb;acc[1]=bb;acc[2]=bb;acc[3]=bb;
      acc = __builtin_amdgcn_mfma_f32_16x16x32_bf16(a0, *(const bf16x8*)&WvF[(size_t)(nt*2+0)*512 + lane*8], acc, 0,0,0);
      acc = __builtin_amdgcn_mfma_f32_16x16x32_bf16(a1, *(const bf16x8*)&WvF[(size_t)(nt*2+1)*512 + lane*8], acc, 0,0,0);
      vfrag[nt] = acc;
    }
  }
  __syncthreads();

  const float scale = 0.04419417382415922f;   // 1/sqrt(512)
  for(int i=tid;i<1152;i+=TPA){
    int q = i%12, kh = i/12; int h2 = kh&7, k2 = kh>>3;
    const float* qp = &U0[q*SRDF + h2*64];
    const float* kp = &U1[k2*SRDF + h2*64];
    float s=0.f;
    #pragma unroll
    for(int d4=0; d4<16; d4++){
      float4 a4 = *(const float4*)&qp[d4*4];
      float4 b4 = *(const float4*)&kp[d4*4];
      s += a4.x*b4.x + a4.y*b4.y + a4.z*b4.z + a4.w*b4.w;
    }
    sS[i] = s*scale;
  }
  __syncthreads();
  {
    int head = w;
    #pragma unroll
    for(int nt=0;nt<4;nt++){
      int col = nt*16 + r15;
      #pragma unroll
      for(int i2=0;i2<4;i2++){ int p = hi*4+i2; if(p<12) U0[p*SRDF + head*64 + col] = vfrag[nt][i2]; }
    }
  }
  if(tid<96){
    float mx=-1e30f;
    for(int q=0;q<12;q++) mx = fmaxf(mx, sS[tid*12+q]);
    float sm=0.f;
    for(int q=0;q<12;q++){ float e = __expf(sS[tid*12+q]-mx); sS[tid*12+q]=e; sm+=e; }
    float inv = 1.f/sm;
    for(int q=0;q<12;q++) sS[tid*12+q] *= inv;
  }
  __syncthreads();

  for(int i=tid;i<6144;i+=TPA){
    int q=i>>9, h2=(i>>6)&7, d=i&63;
    float s=0.f;
    #pragma unroll
    for(int k2=0;k2<12;k2++) s += sS[(k2*8+h2)*12+q]*U0[k2*SRDF+h2*64+d];
    int kk = i & 511;
    SbX[q*512 + (((kk>>3) ^ (q&7))<<3) + (kk&7)] = f2bf(s);
  }
  __syncthreads();

  // fc: 32 col-tiles, 4 per wave
  {
    f32x4 acc[4];
    #pragma unroll
    for(int nt=0;nt<4;nt++){ float bb = bfc[(w*4+nt)*16 + r15]; acc[nt][0]=bb;acc[nt][1]=bb;acc[nt][2]=bb;acc[nt][3]=bb; }
    for(int ks=0;ks<16;ks++){
      int ch = ks*4 + hi;
      bf16x8 a = *(const bf16x8*)&SbX[r15*512 + ((ch ^ (r15&7))<<3)];
      #pragma unroll
      for(int nt=0;nt<4;nt++){
        acc[nt] = __builtin_amdgcn_mfma_f32_16x16x32_bf16(a, *(const bf16x8*)&WfcF[(size_t)((w*4+nt)*16 + ks)*512 + lane*8], acc[nt], 0,0,0);
      }
    }
    #pragma unroll
    for(int nt=0;nt<4;nt++){
      int col = (w*4+nt)*16 + r15;
      #pragma unroll
      for(int i2=0;i2<4;i2++){ int p = hi*4+i2; if(p<12) U1[p*SRDF + col] = acc[nt][i2] + xeg[p*512 + col]; }
    }
  }
  __syncthreads();
  ln_rows<8>(U1, g1, b1n, tid);     // M in U1
  __syncthreads();

  for(int i=tid;i<6144;i+=TPA){
    int r=i>>9, kk=i&511;
    SbX[r*512 + (((kk>>3) ^ (r&7))<<3) + (kk&7)] = f2bf(U1[r*SRDF + kk]);
  }
  __syncthreads();

  // ff1: 16 col-tiles, 2 per wave
  {
    f32x4 acc[2];
    #pragma unroll
    for(int nt=0;nt<2;nt++){ float bb = bff1[(w*2+nt)*16 + r15]; acc[nt][0]=bb;acc[nt][1]=bb;acc[nt][2]=bb;acc[nt][3]=bb; }
    for(int ks=0;ks<16;ks++){
      int ch = ks*4 + hi;
      bf16x8 a = *(const bf16x8*)&SbX[r15*512 + ((ch ^ (r15&7))<<3)];
      #pragma unroll
      for(int nt=0;nt<2;nt++){
        acc[nt] = __builtin_amdgcn_mfma_f32_16x16x32_bf16(a, *(const bf16x8*)&Wff1F[(size_t)((w*2+nt)*16 + ks)*512 + lane*8], acc[nt], 0,0,0);
      }
    }
    #pragma unroll
    for(int nt=0;nt<2;nt++){
      int u = (w*2+nt)*16 + r15;
      #pragma unroll
      for(int i2=0;i2<4;i2++){
        int p = hi*4+i2;
        if(p<12) Mb[p*256 + (((u>>3) ^ (p&7))<<3) + (u&7)] = f2bf(fmaxf(acc[nt][i2], 0.f));
      }
    }
  }
  __syncthreads();

  // ff2: 32 col-tiles, 4 per wave
  {
    f32x4 acc[4];
    #pragma unroll
    for(int nt=0;nt<4;nt++){ float bb = bff2[(w*4+nt)*16 + r15]; acc[nt][0]=bb;acc[nt][1]=bb;acc[nt][2]=bb;acc[nt][3]=bb; }
    for(int ks=0;ks<8;ks++){
      int ch = ks*4 + hi;
      bf16x8 a = *(const bf16x8*)&Mb[r15*256 + ((ch ^ (r15&7))<<3)];
      #pragma unroll
      for(int nt=0;nt<4;nt++){
        acc[nt] = __builtin_amdgcn_mfma_f32_16x16x32_bf16(a, *(const bf16x8*)&Wff2F[(size_t)((w*4+nt)*8 + ks)*512 + lane*8], acc[nt], 0,0,0);
      }
    }
    #pragma unroll
    for(int nt=0;nt<4;nt++){
      int col = (w*4+nt)*16 + r15;
      #pragma unroll
      for(int i2=0;i2<4;i2++){ int p = hi*4+i2; if(p<12) U0[p*SRDF + col] = acc[nt][i2] + U1[p*SRDF + col]; }
    }
  }
  __syncthreads();
  ln_rows<8>(U0, g2, b2n, tid);     // U in U0
  __syncthreads();

  for(int i=tid;i<6144;i+=TPA){
    int r=i>>9, c=i&511;
    U1[r*SRDF+c] = U0[r*SRDF+c] + U1[r*SRDF+c] + xeg[r*512+c];
  }
  __syncthreads();
  for(int i=tid;i<4608;i+=TPA) U0[i] = Wrp[i];
  __syncthreads();
  #pragma unroll
  for(int j=0;j<2;j++){
    int i4 = tid + j*TPA;
    if(i4 < 768){
      int c = i4/12, tq = i4%12; int t0 = tq*4;
      float4 acc = *(const float4*)&brp[t0];
      for(int t96=0;t96<96;t96++){
        int f = c*96 + t96;
        float a = U1[(f>>9)*SRDF + (f&511)];
        float4 w4 = *(const float4*)&U0[t96*48 + t0];
        FMA4(acc, a, w4);
      }
      size_t rb = (((size_t)b*Cc+c)*Nn + n)*Tin + 6 + t0;
      acc.x += resid[rb+0]; acc.y += resid[rb+1]; acc.z += resid[rb+2]; acc.w += resid[rb+3];
      *(float4*)&y[(((size_t)b*Cc+c)*Nn + n)*Tout + t0] = acc;
    }
  }
}

// ---------------- batchnorm ----------------
__global__ __launch_bounds__(TPB) void k_bnstats(const float* __restrict__ y, float* __restrict__ stats){
  int c = blockIdx.x; int tid = threadIdx.x;
  float s=0.f,s2=0.f;
  const int per = Nn*Tout;   // 9936
  for(int idx=tid; idx<Bx*per; idx+=TPB){
    int b = idx/per, r = idx%per;
    float v = y[((size_t)b*Cc+c)*per + r];
    s+=v; s2+=v*v;
  }
  __shared__ float rs[TPB], rs2[TPB];
  rs[tid]=s; rs2[tid]=s2; __syncthreads();
  for(int off=TPB/2; off; off>>=1){ if(tid<off){ rs[tid]+=rs[tid+off]; rs2[tid]+=rs2[tid+off]; } __syncthreads(); }
  if(tid==0){
    float m = rs[0]/(float)(Bx*per);
    float var = rs2[0]/(float)(Bx*per) - m*m;
    stats[c]=m; stats[64+c]=rsqrtf(fmaxf(var,0.f)+EPSF);
  }
}
__global__ __launch_bounds__(TPB) void k_bnout(const float* __restrict__ y, const float* __restrict__ stats,
                                               const float* __restrict__ gbn, const float* __restrict__ bbn,
                                               float* __restrict__ out){
  size_t i = (size_t)blockIdx.x*TPB + threadIdx.x;
  if(i >= (size_t)Bx*Cc*Nn*Tout) return;
  int c = (int)((i/(Nn*Tout))%Cc);
  out[i] = (y[i]-stats[c])*stats[64+c]*gbn[c] + bbn[c];
}

// ---------------- launch ----------------
extern "C" void kernel_launch(void* const* d_in, const int* in_sizes, int n_in,
                              void* d_out, int out_size, void* d_ws, size_t ws_size,
                              hipStream_t stream) {
  const float* x      = (const float*)d_in[0];
  const float* adj    = (const float*)d_in[1];
  const float* Wconv1 = (const float*)d_in[2];
  const float* bconv1 = (const float*)d_in[3];
  const float* gT     = (const float*)d_in[4];
  const float* bT     = (const float*)d_in[5];
  const float* gS     = (const float*)d_in[6];
  const float* bS     = (const float*)d_in[7];
  const float* Wtime  = (const float*)d_in[8];
  const float* btime  = (const float*)d_in[9];
  const float* wq1    = (const float*)d_in[10];
  const float* wv1    = (const float*)d_in[11];
  const float* bias1  = (const float*)d_in[12];
  const float* wq2    = (const float*)d_in[13];
  const float* wv2    = (const float*)d_in[14];
  const float* bias2  = (const float*)d_in[15];
  const float* Wmlp   = (const float*)d_in[16];
  const float* bmlp   = (const float*)d_in[17];
  const float* embT   = (const float*)d_in[18];
  const float* Wq     = (const float*)d_in[19];
  const float* bq     = (const float*)d_in[20];
  const float* Wk     = (const float*)d_in[21];
  const float* bk     = (const float*)d_in[22];
  const float* Wv     = (const float*)d_in[23];
  const float* bv     = (const float*)d_in[24];
  const float* Wfc    = (const float*)d_in[25];
  const float* bfc    = (const float*)d_in[26];
  const float* g1     = (const float*)d_in[27];
  const float* b1n    = (const float*)d_in[28];
  const float* g2     = (const float*)d_in[29];
  const float* b2n    = (const float*)d_in[30];
  const float* Wff1   = (const float*)d_in[31];
  const float* bff1   = (const float*)d_in[32];
  const float* Wff2   = (const float*)d_in[33];
  const float* bff2   = (const float*)d_in[34];
  const float* Wrp    = (const float*)d_in[35];
  const float* brp    = (const float*)d_in[36];
  const float* gbn    = (const float*)d_in[37];
  const float* bbn    = (const float*)d_in[38];

  float* ws = (float*)d_ws;
  float* RESID = ws + O_RESID;
  float* LNTM  = ws + O_LNTM;
  float* LNTR  = ws + O_LNTR;
  float* LNSM  = ws + O_LNSM;
  float* LNSR  = ws + O_LNSR;
  const size_t RSLOT  = (size_t)Bx*128*NP;   // ushorts per RA/RB slot
  const size_t S1SLOT = (size_t)Bx*64*NP;    // ushorts per S1 slot
  ushort* RAx  = (ushort*)(ws + O_XCAT);     // 3 slots
  ushort* RB0  = (ushort*)(ws + O_RB);
  ushort* RB1  = RB0 + RSLOT;                // fills O_RB region exactly
  ushort* RB2  = (ushort*)(ws + O_GACC);     // overlays dead S1 (serial: agg64->gcs128 kills S1, agg128 writes RB2)
  ushort* S1x  = (ushort*)(ws + O_GACC);     // 3 slots (read before RB2 written; RB2 fits in region with S1 dead)
  float* Y     = ws + O_GG;
  float* XE    = ws + O_XE;
  float* BNST  = ws + O_BNST;
  ushort* WTMF = (ushort*)(ws + O_WTM);
  ushort* WTB  = (ushort*)(ws + O_WTB);
  ushort* ADJT = (ushort*)(ws + O_ADJT);
  ushort* HT   = (ushort*)(ws + O_HT);   // in dead H region
  ushort* WQ1B = (ushort*)(ws + O_WQ1B);
  ushort* WV1B = (ushort*)(ws + O_WV1B);
  ushort* WQ2B = (ushort*)(ws + O_WQ2B);
  ushort* WV2B = (ushort*)(ws + O_WV2B);
  ushort* WQT  = (ushort*)(ws + O_WQT);
  ushort* WKT  = (ushort*)(ws + O_WKT);
  ushort* WVT  = (ushort*)(ws + O_WVT);
  ushort* WFCT = (ushort*)(ws + O_WFCT);
  ushort* WF1T = (ushort*)(ws + O_WF1T);
  ushort* WF2T = (ushort*)(ws + O_WF2T);

  k_residual<<<dim3(Nn,Bx),TPB,0,stream>>>(x, Wconv1, bconv1, RESID, LNTM, LNTR);
  k_lnS<<<(Bx*Cc*Tin)/TPB,TPB,0,stream>>>(RESID, LNSM, LNSR);

  // merged fragment-order weight converts (13 jobs, one dispatch; runs before timeconv)
  WJobs jobs;
  jobs.j[0]  = { wq1,  WQ1B, 64,  64,  2,  4,  64*64,   24*4*2*512, 0 };
  jobs.j[1]  = { wv1,  WV1B, 64,  64,  2,  4,  64*64,   24*4*2*512, 0 };
  jobs.j[2]  = { wq2,  WQ2B, 64,  128, 2,  8,  64*128,  24*8*2*512, 0 };
  jobs.j[3]  = { wv2,  WV2B, 64,  128, 2,  8,  64*128,  24*8*2*512, 0 };
  jobs.j[4]  = { Wq,   WQT,  64,  64,  2,  4,  64*64,   4*2*512,    0 };
  jobs.j[5]  = { Wk,   WKT,  64,  64,  2,  4,  64*64,   4*2*512,    0 };
  jobs.j[6]  = { Wv,   WVT,  64,  64,  2,  4,  64*64,   4*2*512,    0 };
  jobs.j[7]  = { Wfc,  WFCT, 512, 512, 16, 32, 512*512, 32*16*512,  0 };
  jobs.j[8]  = { Wff1, WF1T, 512, 256, 16, 16, 512*256, 16*16*512,  0 };
  jobs.j[9]  = { Wff2, WF2T, 256, 512, 8,  32, 256*512, 32*8*512,   0 };
  jobs.j[10] = { adj,  ADJT, 207, 207, 7,  13, Nn*Nn,   3*13*7*512, 0 };
  jobs.j[11] = { Wtime, WTB, 0,   0,   0,  0,  0,       8*18*512,   1 };
  jobs.j[12] = { Wmlp, WTMF, 0,   0,   0,  0,  0,       3*8*12*512, 2 };
  int totalW = 2*(24*4*2*512) + 2*(24*8*2*512) + 3*(4*2*512) + 32*16*512 + 16*16*512 + 32*8*512
             + 3*13*7*512 + 8*18*512 + 3*8*12*512;
  k_wfrag_all<<<(totalW+TPB-1)/TPB,TPB,0,stream>>>(jobs);

  k_htpad<<<(Bx*(NPa-NP)*8+TPB-1)/TPB,TPB,0,stream>>>(HT);
  k_timeconv_mfma<<<dim3(Nn,Bx),TPB,0,stream>>>(RESID, LNTM, LNTR, LNSM, LNSR, gT, bT, gS, bS,
                                                WTB, btime, HT);

  // GCN chain: 3 independent layers batched into 4 wide dispatches
  k_gcs_mfma<64,0><<<dim3(169,3,Bx),TPB,0,stream>>>(HT, WQ1B, WV1B, RAx, 0, RSLOT);
  k_agg_mfma<1><<<dim3(64,Bx*3),TPB,0,stream>>>(RAx, ADJT, bias1, S1x, S1x+S1SLOT, S1x+2*S1SLOT, 64, RSLOT);
  k_gcs_mfma<128,1><<<dim3(169,6,Bx),TPB,0,stream>>>(S1x, WQ2B, WV2B, RAx, S1SLOT, RSLOT);
  k_agg_mfma<0><<<dim3(128,Bx*3),TPB,0,stream>>>(RAx, ADJT, bias2, RB0, RB1, RB2, 128, RSLOT);
  // fused MLP + patch-scramble + emb -> XE (no gg, no k_xe)
  k_mlp_all<<<dim3(Nn,Bx),TPB,0,stream>>>(RB0, RB1, RB2, WTMF, bmlp, embT, XE);
  k_attn<<<dim3(Nn,Bx),TPA,0,stream>>>(XE, RESID, WQT,bq, WKT,bk, WVT,bv, WFCT,bfc,
                                       g1,b1n,g2,b2n, WF1T,bff1, WF2T,bff2, Wrp,brp, Y);
  k_bnstats<<<64,TPB,0,stream>>>(Y, BNST);
  k_bnout<<<(Bx*Cc*Nn*Tout)/TPB,TPB,0,stream>>>(Y, BNST, gbn, bbn, (float*)d_out);
}

// Round 27
// 792.646 us; speedup vs baseline: 1.0125x; 1.0125x over previous
//
#include <hip/hip_runtime.h>
#include <hip/hip_bf16.h>

#define TPB 256
#define TPA 512

constexpr int Bx = 8, Cc = 64, Nn = 207, Tin = 54, Kb = 8;
constexpr int LP = 52, NP = Nn * LP;     // time padded 50->52, flattened node*time positions
constexpr int NPa = 10816;               // NP rounded up to 169*64 for MFMA tiles
constexpr int L50 = 50, Tout = 48;
constexpr int Ee = 512, Pn = 12;
constexpr float EPSF = 1e-5f;
constexpr int SRDF = 516;                // padded row stride for 512-wide f32 LDS rows (2-way bank pattern)

// ---------------- workspace layout (floats) ----------------
constexpr size_t O_RESID = 0;                                   // [B][64][207][54]
constexpr size_t O_LNTM  = O_RESID + (size_t)Bx*Cc*Nn*Tin;
constexpr size_t O_LNTR  = O_LNTM  + (size_t)Bx*Cc*Nn;
constexpr size_t O_LNSM  = O_LNTR  + (size_t)Bx*Cc*Nn;
constexpr size_t O_LNSR  = O_LNSM  + (size_t)Bx*Cc*Tin;
constexpr size_t O_XCAT  = O_LNSR  + (size_t)Bx*Cc*Tin;         // RA bf16 x3 slots (16.53M of 17.17M floats)
constexpr size_t O_RB    = O_XCAT  + (size_t)Bx*192*Nn*Tin;     // RB0,RB1 bf16 slots (fills region exactly)
constexpr size_t O_H     = O_RB    + (size_t)Bx*128*NP;         // HT bf16 [Bx][NPa][64]
constexpr size_t O_GACC  = O_H     + (size_t)Bx*64*NP;          // S1 bf16 x3 slots; RB2 bf16 overlays dead S1 after gcs128
constexpr size_t O_GG    = O_GACC  + (size_t)Bx*128*Nn*Tout;    // Y [B][64][207][48]
constexpr size_t O_XE    = O_GG    + (size_t)Bx*64*Nn*Tout;     // XE [B][207][12][512] (written by mlp_all)
constexpr size_t O_WTT   = O_XE    + (size_t)Bx*Nn*Pn*Ee;       // (unused) 128*192*3
constexpr size_t O_WTM   = O_WTT   + (size_t)128*192*3;         // ushort[3*8*12*512] W_mlp frag bf16
constexpr size_t O_BNST  = O_WTM   + (size_t)128*384*3;         // 128
constexpr size_t O_WTB   = O_BNST + 128;                        // ushort[8*18*512] time-conv bf16 frag weights
constexpr size_t O_ADJT  = O_WTB  + (size_t)128*576/2;          // ushort[3][13*7*512] adj frag bf16
constexpr size_t O_HT    = O_H;                                 // ushort[Bx][NPa][64] in dead H region
// weight frag buffers in high free region (after ADJT):
constexpr size_t O_WQ1B  = O_ADJT + (size_t)3*13*7*512/2;       // ushort[24*4*2*512]
constexpr size_t O_WV1B  = O_WQ1B + (size_t)24*4*2*512/2;
constexpr size_t O_WQ2B  = O_WV1B + (size_t)24*4*2*512/2;       // ushort[24*8*2*512]
constexpr size_t O_WV2B  = O_WQ2B + (size_t)24*8*2*512/2;
constexpr size_t O_WQT   = O_WV2B + (size_t)24*8*2*512/2;       // ushort[4*2*512]
constexpr size_t O_WKT   = O_WQT  + 2048;
constexpr size_t O_WVT   = O_WKT  + 2048;
constexpr size_t O_WFCT  = O_WVT  + 2048;                       // ushort[32*16*512]
constexpr size_t O_WF1T  = O_WFCT + 131072;                     // ushort[16*16*512]
constexpr size_t O_WF2T  = O_WF1T + 65536;                      // ushort[32*8*512]; ends ~65.99M < 67.1M

#define FMA4(acc, sA_, vB_) { (acc).x += (sA_)*(vB_).x; (acc).y += (sA_)*(vB_).y; (acc).z += (sA_)*(vB_).z; (acc).w += (sA_)*(vB_).w; }

typedef __attribute__((ext_vector_type(8))) short bf16x8;
typedef __attribute__((ext_vector_type(4))) float f32x4;

__device__ __forceinline__ float sigm(float x){ return 1.0f/(1.0f+__expf(-x)); }
__device__ __forceinline__ ushort f2bf(float x){ __hip_bfloat16 h = __float2bfloat16(x); return *(ushort*)&h; }

// ---------------- residual = W_conv1 @ x + b, fused lnT stats ----------------
__global__ __launch_bounds__(TPB) void k_residual(const float* __restrict__ x, const float* __restrict__ W,
                                                  const float* __restrict__ bias, float* __restrict__ out,
                                                  float* __restrict__ lnm, float* __restrict__ lnr){
  int n = blockIdx.x, b = blockIdx.y;
  __shared__ __align__(16) float sX[Cc][Tin];
  __shared__ __align__(16) float sW[Cc*Cc];
  __shared__ __align__(16) float sO[Cc][Tin];
  int tid = threadIdx.x;
  for(int i=tid;i<Cc*Tin;i+=TPB){ int c=i/Tin, l=i%Tin; sX[c][l] = x[((size_t)(b*Cc+c)*Nn+n)*Tin+l]; }
  for(int i=tid;i<Cc*Cc;i+=TPB) sW[i]=W[i];
  __syncthreads();
  for(int i=tid;i<Cc*Tin;i+=TPB){
    int o=i/Tin, l=i%Tin; float acc=bias[o];
    #pragma unroll 8
    for(int c=0;c<Cc;c++) acc += sW[o*Cc+c]*sX[c][l];
    out[((size_t)(b*Cc+o)*Nn+n)*Tin+l]=acc;
    sO[o][l]=acc;
  }
  __syncthreads();
  if(tid < Cc){
    float s=0.f,s2=0.f;
    for(int l=0;l<Tin;l++){ float v=sO[tid][l]; s+=v; s2+=v*v; }
    float m=s*(1.f/Tin); float var=s2*(1.f/Tin)-m*m;
    int row = (b*Cc+tid)*Nn + n;
    lnm[row]=m; lnr[row]=rsqrtf(fmaxf(var,0.f)+EPSF);
  }
}

// ---------------- lnS stats ----------------
__global__ __launch_bounds__(TPB) void k_lnS(const float* __restrict__ r, float* __restrict__ mean, float* __restrict__ rstd){
  int row = blockIdx.x*TPB + threadIdx.x;       // (b*Cc+c)*Tin + l
  if(row >= Bx*Cc*Tin) return;
  int l = row % Tin; int bc = row / Tin;
  const float* p = r + (size_t)bc*Nn*Tin + l;
  float s=0.f,s2=0.f;
  for(int n=0;n<Nn;n++){ float v=p[(size_t)n*Tin]; s+=v; s2+=v*v; }
  float m=s*(1.f/Nn); float var=s2*(1.f/Nn)-m*m;
  mean[row]=m; rstd[row]=rsqrtf(fmaxf(var,0.f)+EPSF);
}

// ---------------- merged converter (14 jobs: generic/timeconv/mlp/htpad-zero) ----------------
struct WJob { const float* W; ushort* F; int K, N, KS, NT, sStride, total, type; };
struct WJobs { WJob j[14]; };

__global__ __launch_bounds__(TPB) void k_wfrag_all(WJobs jobs){
  int gi = blockIdx.x*TPB + threadIdx.x;
  for(int seg=0; seg<14; seg++){
    const WJob J = jobs.j[seg];
    if(gi < J.total){
      int i = gi;
      if(J.type == 3){                        // HT pad zero-fill
        int b = i / ((NPa-NP)*64); int r = i % ((NPa-NP)*64);
        J.F[((size_t)b*NPa + NP)*64 + r] = 0;
        return;
      }
      int j = i & 7; int lane = (i>>3) & 63;
      int t = i >> 9;
      int r15 = lane & 15, hi = lane >> 4;
      float v;
      if(J.type == 0){
        int ks = t % J.KS; int r = t / J.KS; int colTile = r % J.NT; int s = r / J.NT;
        int k = ks*32 + hi*8 + j, col = colTile*16 + r15;
        v = (k < J.K && col < J.N) ? J.W[(size_t)s*J.sStride + (size_t)k*J.N + col] : 0.f;
      } else if(J.type == 1){
        int ks = t % 18; int colTile = t / 18;
        int k = ks*32 + hi*8 + j, o = colTile*16 + r15;
        int kt = k/192, ci = k - kt*192;
        v = J.W[(size_t)(o*192+ci)*3 + kt];
      } else {
        int ks = t % 12; int r = t / 12; int colTile = r & 7; int layer = r >> 3;
        int k = ks*32 + hi*8 + j;
        int kt = k >> 7, ci = k & 127;
        int o = colTile*16 + r15;
        v = J.W[(size_t)(o*384 + layer*128 + ci)*3 + kt];
      }
      J.F[i] = f2bf(v);
      return;
    }
    gi -= J.total;
  }
}

// ---------------- fused xcat+dilated time conv (dil=2) + GLU via MFMA -> HT bf16 [b][p][64] ----------------
__global__ __launch_bounds__(TPB) void k_timeconv_mfma(const float* __restrict__ resid,
    const float* __restrict__ tm, const float* __restrict__ tr,
    const float* __restrict__ sm, const float* __restrict__ sr,
    const float* __restrict__ gT, const float* __restrict__ bT,
    const float* __restrict__ gS, const float* __restrict__ bS,
    const ushort* __restrict__ WF, const float* __restrict__ bias, ushort* __restrict__ HT){
  int n = blockIdx.x, b = blockIdx.y;
  constexpr int XS = 200;
  __shared__ __align__(16) ushort sXT[68*XS];
  int tid = threadIdx.x;
  for(int i=tid; i<14*XS; i+=TPB) sXT[54*XS + i] = 0;
  float gSn = gS[n], bSn = bS[n];
  for(int i=tid; i<64*54; i+=TPB){
    int cm = i/54, l = i%54;
    int rowT = (b*Cc+cm)*Nn + n;
    float r = resid[(size_t)rowT*Tin + l];
    float v1 = (r - tm[rowT]) * tr[rowT] * gT[l] + bT[l];
    int rowS = (b*Cc+cm)*Tin + l;
    float v2 = (r - sm[rowS]) * sr[rowS] * gSn + bSn;
    sXT[l*XS + cm]        = f2bf(r);
    sXT[l*XS + 64 + cm]   = f2bf(v1);
    sXT[l*XS + 128 + cm]  = f2bf(v2);
  }
  __syncthreads();
  int lane = tid & 63, w = tid >> 6;
  int r15 = lane & 15, hi = lane >> 4;
  float b0 = bias[w*16 + r15], b1 = bias[w*16 + 64 + r15];
  f32x4 acc0[4], acc1[4];
  #pragma unroll
  for(int tt=0;tt<4;tt++){
    acc0[tt][0]=b0; acc0[tt][1]=b0; acc0[tt][2]=b0; acc0[tt][3]=b0;
    acc1[tt][0]=b1; acc1[tt][1]=b1; acc1[tt][2]=b1; acc1[tt][3]=b1;
  }
  const ushort* wp0 = WF + ((size_t)w*18)*512 + lane*8;
  const ushort* wp1 = WF + ((size_t)(w+4)*18)*512 + lane*8;
  #pragma unroll 2
  for(int ks=0; ks<18; ks++){
    int k0 = ks*32 + hi*8;
    int kt = k0/192, ci0 = k0 - kt*192;
    bf16x8 bw0 = *(const bf16x8*)&wp0[(size_t)ks*512];
    bf16x8 bw1 = *(const bf16x8*)&wp1[(size_t)ks*512];
    #pragma unroll
    for(int tt=0;tt<4;tt++){
      bf16x8 ax = *(const bf16x8*)&sXT[(tt*16 + r15 + 2*kt)*XS + ci0];
      acc0[tt] = __builtin_amdgcn_mfma_f32_16x16x32_bf16(ax, bw0, acc0[tt], 0,0,0);
      acc1[tt] = __builtin_amdgcn_mfma_f32_16x16x32_bf16(ax, bw1, acc1[tt], 0,0,0);
    }
  }
  ushort* htp = HT + ((size_t)b*NPa + (size_t)n*LP)*64;
  int c = w*16 + r15;
  #pragma unroll
  for(int tt=0;tt<4;tt++){
    int t0 = tt*16 + hi*4;
    #pragma unroll
    for(int i=0;i<4;i++){
      int t = t0 + i;
      if(t < L50) htp[(size_t)t*64 + c] = f2bf(tanhf(acc0[tt][i])*sigm(acc1[tt][i]));
    }
  }
  if(tid < 128){ int cz = tid >> 1, tz = 50 + (tid & 1); htp[(size_t)tz*64 + cz] = 0; }
}

// ---------------- gated multi-basis GCN einsum via MFMA; all 3 layers in one dispatch ----------------
// TR=0: input XT bf16 [b][NPa][64] shared; TR=1: per-layer input bf16 [b][64][NP], both d-halves in-block
template<int D, int TR>
__global__ __launch_bounds__(TPB) void k_gcs_mfma(const ushort* __restrict__ XT,
    const ushort* __restrict__ wqF, const ushort* __restrict__ wvF,
    ushort* __restrict__ S, size_t inSlot, size_t outSlot){
  constexpr int Dt = D/16;
  constexpr int NDH = D/64;          // d-halves processed per block
  constexpr size_t WSTR = (size_t)Kb*Dt*2*512;
  int p0 = blockIdx.x*64;
  int b = blockIdx.z;
  int iy = blockIdx.y;               // GCN layer index i in [0,3)
  int tid = threadIdx.x;
  int lane = tid & 63, w = tid >> 6;
  const ushort* wqB = wqF + iy*WSTR;
  const ushort* wvB = wvF + iy*WSTR;
  ushort* Sb = S + iy*outSlot;
  __shared__ __align__(16) ushort sX[64*64];
  if constexpr(TR){
    const ushort* Xp = XT + iy*inSlot;
    __shared__ __align__(16) ushort sT2[64*66];
    for(int i=tid;i<4096;i+=TPB){ int c=i>>6, col=i&63; int p=p0+col;
      sT2[c*66+col] = (p<NP) ? Xp[((size_t)(b*64+c))*NP + p] : (ushort)0; }
    __syncthreads();
    for(int i=tid;i<512;i+=TPB){
      int row=i>>3, c8=(i&7)<<3;
      ushort u[8];
      #pragma unroll
      for(int j=0;j<8;j++) u[j] = sT2[(c8+j)*66 + row];
      *(uint4*)&sX[row*64 + (c8 ^ ((row&7)<<3))] = *(uint4*)u;
    }
  } else {
    for(int i=tid;i<512;i+=TPB){
      int row=i>>3, c8=(i&7)<<3;
      uint4 v = *(const uint4*)&XT[((size_t)b*NPa + p0 + row)*64 + c8];
      *(uint4*)&sX[row*64 + (c8 ^ ((row&7)<<3))] = v;
    }
  }
  __syncthreads();
  int r15 = lane & 15, hi = lane >> 4;
  bf16x8 bf[4][2];
  #pragma unroll
  for(int pt=0;pt<4;pt++){
    int row = pt*16 + r15;
    int sw = (row&7)<<3;
    int cu0 = hi*8;
    bf[pt][0] = *(const bf16x8*)&sX[row*64 + (cu0 ^ sw)];
    bf[pt][1] = *(const bf16x8*)&sX[row*64 + ((cu0+32) ^ sw)];
  }
  #pragma unroll
  for(int dh=0; dh<NDH; dh++){
    int dTile = dh*4 + w;
    int d0 = dh*64 + (w<<4);
    f32x4 acc[4];
    #pragma unroll
    for(int pt=0;pt<4;pt++){ acc[pt][0]=0.f; acc[pt][1]=0.f; acc[pt][2]=0.f; acc[pt][3]=0.f; }
    const ushort* wqp = wqB + ((size_t)dTile*2)*512 + lane*8;
    const ushort* wvp = wvB + ((size_t)dTile*2)*512 + lane*8;
    for(int k=0;k<Kb;k++){
      bf16x8 aq0 = *(const bf16x8*)&wqp[0];
      bf16x8 aq1 = *(const bf16x8*)&wqp[512];
      bf16x8 av0 = *(const bf16x8*)&wvp[0];
      bf16x8 av1 = *(const bf16x8*)&wvp[512];
      wqp += (size_t)Dt*2*512; wvp += (size_t)Dt*2*512;
      #pragma unroll
      for(int pt=0;pt<4;pt++){
        f32x4 q; q[0]=0.f;q[1]=0.f;q[2]=0.f;q[3]=0.f;
        f32x4 v; v[0]=0.f;v[1]=0.f;v[2]=0.f;v[3]=0.f;
        q = __builtin_amdgcn_mfma_f32_16x16x32_bf16(aq0, bf[pt][0], q, 0,0,0);
        q = __builtin_amdgcn_mfma_f32_16x16x32_bf16(aq1, bf[pt][1], q, 0,0,0);
        v = __builtin_amdgcn_mfma_f32_16x16x32_bf16(av0, bf[pt][0], v, 0,0,0);
        v = __builtin_amdgcn_mfma_f32_16x16x32_bf16(av1, bf[pt][1], v, 0,0,0);
        #pragma unroll
        for(int i=0;i<4;i++) acc[pt][i] += v[i]*sigm(q[i]);
      }
    }
    #pragma unroll
    for(int pt=0;pt<4;pt++){
      int p = p0 + pt*16 + r15;
      if(p < NP){
        #pragma unroll
        for(int i=0;i<4;i++){
          int d = d0 + hi*4 + i;
          Sb[((size_t)b*D + d)*NP + p] = f2bf(acc[pt][i]);
        }
      }
    }
  }
}

// ---------------- adjacency aggregation via MFMA; all 3 layers in one dispatch ----------------
template<int RELU>
__global__ __launch_bounds__(TPB) void k_agg_mfma(const ushort* __restrict__ S, const ushort* __restrict__ adjF,
                                                  const float* __restrict__ bias,
                                                  ushort* __restrict__ O0, ushort* __restrict__ O1, ushort* __restrict__ O2,
                                                  int D, size_t inSlot){
  int d = blockIdx.x;
  int by = blockIdx.y;
  int b = by / 3, li = by % 3;          // li = GCN layer index
  int bd = b*D + d;
  const ushort* adjL = adjF + (size_t)li*13*7*512;
  constexpr int SST = 232;
  __shared__ __align__(16) ushort sB[64*SST];
  int tid = threadIdx.x;
  for(int i=tid*8; i<64*SST; i+=TPB*8){ uint4 z; z.x=0;z.y=0;z.z=0;z.w=0; *(uint4*)&sB[i]=z; }
  __syncthreads();
  const ushort* Sp = S + li*inSlot + (size_t)bd*NP;
  for(int i=tid; i<NP; i+=TPB){
    int nn = i/52, l = i - nn*52;
    sB[l*SST + nn] = Sp[i];
  }
  __syncthreads();
  int lane = tid & 63, w = tid >> 6;
  int r15 = lane & 15, hi = lane >> 4;
  float bb = bias[li*D + d];
  ushort* Ob = (li==0) ? O0 : (li==1 ? O1 : O2);
  ushort* Op = Ob + (size_t)bd*NP;
  for(int k2t = w; k2t < 13; k2t += 4){
    f32x4 acc[4];
    #pragma unroll
    for(int lt=0;lt<4;lt++){ acc[lt][0]=0;acc[lt][1]=0;acc[lt][2]=0;acc[lt][3]=0; }
    #pragma unroll
    for(int ks=0; ks<7; ks++){
      bf16x8 a = *(const bf16x8*)&adjL[((size_t)(k2t*7 + ks))*512 + lane*8];
      #pragma unroll
      for(int lt=0;lt<4;lt++){
        bf16x8 bfr = *(const bf16x8*)&sB[(lt*16+r15)*SST + ks*32 + hi*8];
        acc[lt] = __builtin_amdgcn_mfma_f32_16x16x32_bf16(a, bfr, acc[lt], 0,0,0);
      }
    }
    #pragma unroll
    for(int lt=0;lt<4;lt++){
      #pragma unroll
      for(int i2=0;i2<4;i2++){
        int k2 = k2t*16 + hi*4 + i2;
        int l  = lt*16 + r15;
        if(k2 < Nn && l < LP){
          float v = acc[lt][i2] + bb;
          if(RELU) v = fmaxf(v, 0.f);
          Op[(size_t)k2*LP + l] = f2bf(v);
        }
      }
    }
  }
}

// ---------------- fused MLP conv (3 layers) + patch-scramble + emb -> XE directly ----------------
__global__ __launch_bounds__(TPB) void k_mlp_all(const ushort* __restrict__ RB0, const ushort* __restrict__ RB1,
                                                 const ushort* __restrict__ RB2, const ushort* __restrict__ WF,
                                                 const float* __restrict__ bm, const float* __restrict__ emb,
                                                 float* __restrict__ xe){
  int n = blockIdx.x, b = blockIdx.y;
  constexpr int CS = 136;
  __shared__ __align__(16) ushort sLT[3*52*CS];
  int tid = threadIdx.x;
  {
    const ushort* Rp = RB0;
    for(int i=tid;i<6656;i+=TPB){ int c=i/52, l=i%52; sLT[0*52*CS + l*CS + c] = Rp[(((size_t)b*128+c)*Nn + n)*LP + l]; }
    Rp = RB1;
    for(int i=tid;i<6656;i+=TPB){ int c=i/52, l=i%52; sLT[1*52*CS + l*CS + c] = Rp[(((size_t)b*128+c)*Nn + n)*LP + l]; }
    Rp = RB2;
    for(int i=tid;i<6656;i+=TPB){ int c=i/52, l=i%52; sLT[2*52*CS + l*CS + c] = Rp[(((size_t)b*128+c)*Nn + n)*LP + l]; }
  }
  __syncthreads();
  int lane = tid & 63, w = tid >> 6;
  int r15 = lane & 15, hi = lane >> 4;
  f32x4 acc0[3], acc1[3];
  #pragma unroll
  for(int tt=0;tt<3;tt++){
    acc0[tt][0]=0;acc0[tt][1]=0;acc0[tt][2]=0;acc0[tt][3]=0;
    acc1[tt][0]=0;acc1[tt][1]=0;acc1[tt][2]=0;acc1[tt][3]=0;
  }
  #pragma unroll
  for(int layer=0; layer<3; layer++){
    const ushort* wp0 = WF + ((size_t)(layer*8 + w)*12)*512 + lane*8;
    const ushort* wp1 = WF + ((size_t)(layer*8 + w+4)*12)*512 + lane*8;
    const ushort* sL = &sLT[layer*52*CS];
    #pragma unroll 3
    for(int ks=0; ks<12; ks++){
      int kt = ks>>2, ci0 = (ks&3)*32 + hi*8;
      bf16x8 bw0 = *(const bf16x8*)&wp0[(size_t)ks*512];
      bf16x8 bw1 = *(const bf16x8*)&wp1[(size_t)ks*512];
      #pragma unroll
      for(int tt=0;tt<3;tt++){
        bf16x8 ax = *(const bf16x8*)&sL[(tt*16 + r15 + kt)*CS + ci0];
        acc0[tt] = __builtin_amdgcn_mfma_f32_16x16x32_bf16(ax, bw0, acc0[tt], 0,0,0);
        acc1[tt] = __builtin_amdgcn_mfma_f32_16x16x32_bf16(ax, bw1, acc1[tt], 0,0,0);
      }
    }
  }
  int o = w*16 + r15;
  float b0 = bm[o], b1 = bm[o+64];
  float* xeb = xe + (size_t)b*1271808;
  int off0 = o*19872 + n*96;
  #pragma unroll
  for(int tt=0;tt<3;tt++){
    #pragma unroll
    for(int i2=0;i2<4;i2++){
      int tq = tt*16 + hi*4 + i2;
      float v = tanhf(acc0[tt][i2] + b0)*sigm(acc1[tt][i2] + b1);
      int p1 = tq>>2, j1 = tq&3;
      int offa = off0 + p1*8 + j1;
      xeb[offa] = v + emb[(size_t)((offa>>9)%12)*Ee + (offa&511)];
      if(tq >= 4){
        int offb = off0 + (p1-1)*8 + j1 + 4;
        xeb[offb] = v + emb[(size_t)((offb>>9)%12)*Ee + (offb&511)];
      }
    }
  }
  // pad entries r2 in [92,96): t>=48 -> emb only (one per thread; 64 c x 4)
  {
    int o2 = tid >> 2, r2 = 92 + (tid & 3);
    int offp = o2*19872 + n*96 + r2;
    xeb[offp] = emb[(size_t)((offp>>9)%12)*Ee + (offp&511)];
  }
}

// ---------------- per-row LN helper (rows of 512, stride SRDF, in LDS); NW waves ----------------
template<int NW>
__device__ __forceinline__ void ln_rows(float* buf, const float* __restrict__ g, const float* __restrict__ be, int tid){
  int lane = tid & 63, wv = tid >> 6;
  for(int r = wv; r < 12; r += NW){
    float s=0.f, s2=0.f;
    #pragma unroll
    for(int j=0;j<8;j++){ float v = buf[r*SRDF + j*64 + lane]; s+=v; s2+=v*v; }
    #pragma unroll
    for(int off=32; off; off>>=1){ s += __shfl_xor(s,off); s2 += __shfl_xor(s2,off); }
    float m = s*(1.f/512.f);
    float rstd = rsqrtf(fmaxf(s2*(1.f/512.f)-m*m, 0.f)+EPSF);
    #pragma unroll
    for(int j=0;j<8;j++){ int e = j*64+lane; float v = buf[r*SRDF+e];
      buf[r*SRDF+e] = (v-m)*rstd*g[e] + be[e]; }
  }
}

// ---------------- fused per-(b,n) transformer, MFMA GEMM phases; 512 threads (8 waves) ----------------
__global__ __launch_bounds__(TPA,2) void k_attn(
    const float* __restrict__ xe, const float* __restrict__ resid,
    const ushort* __restrict__ WqF, const float* __restrict__ bq,
    const ushort* __restrict__ WkF, const float* __restrict__ bk,
    const ushort* __restrict__ WvF, const float* __restrict__ bv,
    const ushort* __restrict__ WfcF, const float* __restrict__ bfc,
    const float* __restrict__ g1, const float* __restrict__ b1n,
    const float* __restrict__ g2, const float* __restrict__ b2n,
    const ushort* __restrict__ Wff1F, const float* __restrict__ bff1,
    const ushort* __restrict__ Wff2F, const float* __restrict__ bff2,
    const float* __restrict__ Wrp, const float* __restrict__ brp,
    float* __restrict__ y)
{
  int n = blockIdx.x, b = blockIdx.y;
  __shared__ __align__(16) ushort SbX[16*512];
  __shared__ __align__(16) ushort Mb[16*256];
  __shared__ __align__(16) float U0[12*SRDF];
  __shared__ __align__(16) float U1[12*SRDF];
  __shared__ __align__(16) float sS[1160];
  int tid = threadIdx.x;
  int lane = tid & 63, w = tid >> 6;          // w in [0,8)
  int r15 = lane & 15, hi = lane >> 4;
  const float* __restrict__ xeg = xe + ((size_t)b*Nn + n)*6144;

  for(int i=tid;i<1024;i+=TPA){
    int r = i>>6, ch = i&63;
    ushort u[8];
    if(r<12){
      const float* s = &xeg[r*512 + ch*8];
      #pragma unroll
      for(int j=0;j<8;j++) u[j] = f2bf(s[j]);
    } else {
      #pragma unroll
      for(int j=0;j<8;j++) u[j] = 0;
    }
    *(uint4*)&SbX[r*512 + ((ch ^ (r&7))<<3)] = *(uint4*)u;
  }
  for(int i=tid;i<128;i+=TPA){
    int r = 12 + (i>>5), ch = i&31;
    uint4 z; z.x=0;z.y=0;z.z=0;z.w=0;
    *(uint4*)&Mb[r*256 + ch*8] = z;
  }
  __syncthreads();

  // QKV: one head per wave
  f32x4 vfrag[4];
  {
    int head = w;
    bf16x8 a0, a1;
    { int ch0 = head*8 + hi, ch1 = head*8 + 4 + hi;
      a0 = *(const bf16x8*)&SbX[r15*512 + ((ch0 ^ (r15&7))<<3)];
      a1 = *(const bf16x8*)&SbX[r15*512 + ((ch1 ^ (r15&7))<<3)]; }
    #pragma unroll
    for(int nt=0;nt<4;nt++){
      int col = nt*16 + r15;
      float bb = bq[col];
      f32x4 acc; acc[0]=bb;acc[1]=bb;acc[2]=bb;acc[3]=bb;
      acc = __builtin_amdgcn_mfma_f32_16x16x32_bf16(a0, *(const bf16x8*)&WqF[(size_t)(nt*2+0)*512 + lane*8], acc, 0,0,0);
      acc = __builtin_amdgcn_mfma_f32_16x16x32_bf16(a1, *(const bf16x8*)&WqF[(size_t)(nt*2+1)*512 + lane*8], acc, 0,0,0);
      #pragma unroll
      for(int i2=0;i2<4;i2++){ int p = hi*4+i2; if(p<12) U0[p*SRDF + head*64 + col] = acc[i2]; }
    }
    #pragma unroll
    for(int nt=0;nt<4;nt++){
      int col = nt*16 + r15;
      float bb = bk[col];
      f32x4 acc; acc[0]=bb;acc[1]=bb;acc[2]=bb;acc[3]=bb;
      acc = __builtin_amdgcn_mfma_f32_16x16x32_bf16(a0, *(const bf16x8*)&WkF[(size_t)(nt*2+0)*512 + lane*8], acc, 0,0,0);
      acc = __builtin_amdgcn_mfma_f32_16x16x32_bf16(a1, *(const bf16x8*)&WkF[(size_t)(nt*2+1)*512 + lane*8], acc, 0,0,0);
      #pragma unroll
      for(int i2=0;i2<4;i2++){ int p = hi*4+i2; if(p<12) U1[p*SRDF + head*64 + col] = acc[i2]; }
    }
    #pragma unroll
    for(int nt=0;nt<4;nt++){
      int col = nt*16 + r15;
      float bb = bv[col];
      f32x4 acc; acc[0]=bb;acc[1]=bb;acc[2]=bb;acc[3]=bb;
      acc = __builtin_amdgcn_mfma_f32_16x16x32_bf16(a0, *(const bf16x8*)&WvF[(size_t)(nt*2+0)*512 + lane*8], acc, 0,0,0);
      acc = __builtin_amdgcn_mfma_f32_16x16x32_bf16(a1, *(const bf16x8*)&WvF[(size_t)(nt*2+1)*512 + lane*8], acc, 0,0,0);
      vfrag[nt] = acc;
    }
  }
  __syncthreads();

  const float scale = 0.04419417382415922f;   // 1/sqrt(512)
  for(int i=tid;i<1152;i+=TPA){
    int q = i%12, kh = i/12; int h2 = kh&7, k2 = kh>>3;
    const float* qp = &U0[q*SRDF + h2*64];
    const float* kp = &U1[k2*SRDF + h2*64];
    float s=0.f;
    #pragma unroll
    for(int d4=0; d4<16; d4++){
      float4 a4 = *(const float4*)&qp[d4*4];
      float4 b4 = *(const float4*)&kp[d4*4];
      s += a4.x*b4.x + a4.y*b4.y + a4.z*b4.z + a4.w*b4.w;
    }
    sS[i] = s*scale;
  }
  __syncthreads();
  {
    int head = w;
    #pragma unroll
    for(int nt=0;nt<4;nt++){
      int col = nt*16 + r15;
      #pragma unroll
      for(int i2=0;i2<4;i2++){ int p = hi*4+i2; if(p<12) U0[p*SRDF + head*64 + col] = vfrag[nt][i2]; }
    }
  }
  if(tid<96){
    float mx=-1e30f;
    for(int q=0;q<12;q++) mx = fmaxf(mx, sS[tid*12+q]);
    float sm=0.f;
    for(int q=0;q<12;q++){ float e = __expf(sS[tid*12+q]-mx); sS[tid*12+q]=e; sm+=e; }
    float inv = 1.f/sm;
    for(int q=0;q<12;q++) sS[tid*12+q] *= inv;
  }
  __syncthreads();

  for(int i=tid;i<6144;i+=TPA){
    int q=i>>9, h2=(i>>6)&7, d=i&63;
    float s=0.f;
    #pragma unroll
    for(int k2=0;k2<12;k2++) s += sS[(k2*8+h2)*12+q]*U0[k2*SRDF+h2*64+d];
    int kk = i & 511;
    SbX[q*512 + (((kk>>3) ^ (q&7))<<3) + (kk&7)] = f2bf(s);
  }
  __syncthreads();

  // fc: 32 col-tiles, 4 per wave
  {
    f32x4 acc[4];
    #pragma unroll
    for(int nt=0;nt<4;nt++){ float bb = bfc[(w*4+nt)*16 + r15]; acc[nt][0]=bb;acc[nt][1]=bb;acc[nt][2]=bb;acc[nt][3]=bb; }
    for(int ks=0;ks<16;ks++){
      int ch = ks*4 + hi;
      bf16x8 a = *(const bf16x8*)&SbX[r15*512 + ((ch ^ (r15&7))<<3)];
      #pragma unroll
      for(int nt=0;nt<4;nt++){
        acc[nt] = __builtin_amdgcn_mfma_f32_16x16x32_bf16(a, *(const bf16x8*)&WfcF[(size_t)((w*4+nt)*16 + ks)*512 + lane*8], acc[nt], 0,0,0);
      }
    }
    #pragma unroll
    for(int nt=0;nt<4;nt++){
      int col = (w*4+nt)*16 + r15;
      #pragma unroll
      for(int i2=0;i2<4;i2++){ int p = hi*4+i2; if(p<12) U1[p*SRDF + col] = acc[nt][i2] + xeg[p*512 + col]; }
    }
  }
  __syncthreads();
  ln_rows<8>(U1, g1, b1n, tid);     // M in U1
  __syncthreads();

  for(int i=tid;i<6144;i+=TPA){
    int r=i>>9, kk=i&511;
    SbX[r*512 + (((kk>>3) ^ (r&7))<<3) + (kk&7)] = f2bf(U1[r*SRDF + kk]);
  }
  __syncthreads();

  // ff1: 16 col-tiles, 2 per wave
  {
    f32x4 acc[2];
    #pragma unroll
    for(int nt=0;nt<2;nt++){ float bb = bff1[(w*2+nt)*16 + r15]; acc[nt][0]=bb;acc[nt][1]=bb;acc[nt][2]=bb;acc[nt][3]=bb; }
    for(int ks=0;ks<16;ks++){
      int ch = ks*4 + hi;
      bf16x8 a = *(const bf16x8*)&SbX[r15*512 + ((ch ^ (r15&7))<<3)];
      #pragma unroll
      for(int nt=0;nt<2;nt++){
        acc[nt] = __builtin_amdgcn_mfma_f32_16x16x32_bf16(a, *(const bf16x8*)&Wff1F[(size_t)((w*2+nt)*16 + ks)*512 + lane*8], acc[nt], 0,0,0);
      }
    }
    #pragma unroll
    for(int nt=0;nt<2;nt++){
      int u = (w*2+nt)*16 + r15;
      #pragma unroll
      for(int i2=0;i2<4;i2++){
        int p = hi*4+i2;
        if(p<12) Mb[p*256 + (((u>>3) ^ (p&7))<<3) + (u&7)] = f2bf(fmaxf(acc[nt][i2], 0.f));
      }
    }
  }
  __syncthreads();

  // ff2: 32 col-tiles, 4 per wave
  {
    f32x4 acc[4];
    #pragma unroll
    for(int nt=0;nt<4;nt++){ float bb = bff2[(w*4+nt)*16 + r15]; acc[nt][0]=bb;acc[nt][1]=bb;acc[nt][2]=bb;acc[nt][3]=bb; }
    for(int ks=0;ks<8;ks++){
      int ch = ks*4 + hi;
      bf16x8 a = *(const bf16x8*)&Mb[r15*256 + ((ch ^ (r15&7))<<3)];
      #pragma unroll
      for(int nt=0;nt<4;nt++){
        acc[nt] = __builtin_amdgcn_mfma_f32_16x16x32_bf16(a, *(const bf16x8*)&Wff2F[(size_t)((w*4+nt)*8 + ks)*512 + lane*8], acc[nt], 0,0,0);
      }
    }
    #pragma unroll
    for(int nt=0;nt<4;nt++){
      int col = (w*4+nt)*16 + r15;
      #pragma unroll
      for(int i2=0;i2<4;i2++){ int p = hi*4+i2; if(p<12) U0[p*SRDF + col] = acc[nt][i2] + U1[p*SRDF + col]; }
    }
  }
  __syncthreads();
  ln_rows<8>(U0, g2, b2n, tid);     // U in U0
  __syncthreads();

  for(int i=tid;i<6144;i+=TPA){
    int r=i>>9, c=i&511;
    U1[r*SRDF+c] = U0[r*SRDF+c] + U1[r*SRDF+c] + xeg[r*512+c];
  }
  __syncthreads();
  for(int i=tid;i<4608;i+=TPA) U0[i] = Wrp[i];
  __syncthreads();
  #pragma unroll
  for(int j=0;j<2;j++){
    int i4 = tid + j*TPA;
    if(i4 < 768){
      int c = i4/12, tq = i4%12; int t0 = tq*4;
      float4 acc = *(const float4*)&brp[t0];
      for(int t96=0;t96<96;t96++){
        int f = c*96 + t96;
        float a = U1[(f>>9)*SRDF + (f&511)];
        float4 w4 = *(const float4*)&U0[t96*48 + t0];
        FMA4(acc, a, w4);
      }
      size_t rb = (((size_t)b*Cc+c)*Nn + n)*Tin + 6 + t0;
      acc.x += resid[rb+0]; acc.y += resid[rb+1]; acc.z += resid[rb+2]; acc.w += resid[rb+3];
      *(float4*)&y[(((size_t)b*Cc+c)*Nn + n)*Tout + t0] = acc;
    }
  }
}

// ---------------- batchnorm ----------------
__global__ __launch_bounds__(TPB) void k_bnstats(const float* __restrict__ y, float* __restrict__ stats){
  int c = blockIdx.x; int tid = threadIdx.x;
  float s=0.f,s2=0.f;
  const int per = Nn*Tout;   // 9936
  for(int idx=tid; idx<Bx*per; idx+=TPB){
    int b = idx/per, r = idx%per;
    float v = y[((size_t)b*Cc+c)*per + r];
    s+=v; s2+=v*v;
  }
  __shared__ float rs[TPB], rs2[TPB];
  rs[tid]=s; rs2[tid]=s2; __syncthreads();
  for(int off=TPB/2; off; off>>=1){ if(tid<off){ rs[tid]+=rs[tid+off]; rs2[tid]+=rs2[tid+off]; } __syncthreads(); }
  if(tid==0){
    float m = rs[0]/(float)(Bx*per);
    float var = rs2[0]/(float)(Bx*per) - m*m;
    stats[c]=m; stats[64+c]=rsqrtf(fmaxf(var,0.f)+EPSF);
  }
}
__global__ __launch_bounds__(TPB) void k_bnout(const float* __restrict__ y, const float* __restrict__ stats,
                                               const float* __restrict__ gbn, const float* __restrict__ bbn,
                                               float* __restrict__ out){
  size_t i = (size_t)blockIdx.x*TPB + threadIdx.x;
  if(i >= (size_t)Bx*Cc*Nn*Tout) return;
  int c = (int)((i/(Nn*Tout))%Cc);
  out[i] = (y[i]-stats[c])*stats[64+c]*gbn[c] + bbn[c];
}

// ---------------- launch ----------------
extern "C" void kernel_launch(void* const* d_in, const int* in_sizes, int n_in,
                              void* d_out, int out_size, void* d_ws, size_t ws_size,
                              hipStream_t stream) {
  const float* x      = (const float*)d_in[0];
  const float* adj    = (const float*)d_in[1];
  const float* Wconv1 = (const float*)d_in[2];
  const float* bconv1 = (const float*)d_in[3];
  const float* gT     = (const float*)d_in[4];
  const float* bT     = (const float*)d_in[5];
  const float* gS     = (const float*)d_in[6];
  const float* bS     = (const float*)d_in[7];
  const float* Wtime  = (const float*)d_in[8];
  const float* btime  = (const float*)d_in[9];
  const float* wq1    = (const float*)d_in[10];
  const float* wv1    = (const float*)d_in[11];
  const float* bias1  = (const float*)d_in[12];
  const float* wq2    = (const float*)d_in[13];
  const float* wv2    = (const float*)d_in[14];
  const float* bias2  = (const float*)d_in[15];
  const float* Wmlp   = (const float*)d_in[16];
  const float* bmlp   = (const float*)d_in[17];
  const float* embT   = (const float*)d_in[18];
  const float* Wq     = (const float*)d_in[19];
  const float* bq     = (const float*)d_in[20];
  const float* Wk     = (const float*)d_in[21];
  const float* bk     = (const float*)d_in[22];
  const float* Wv     = (const float*)d_in[23];
  const float* bv     = (const float*)d_in[24];
  const float* Wfc    = (const float*)d_in[25];
  const float* bfc    = (const float*)d_in[26];
  const float* g1     = (const float*)d_in[27];
  const float* b1n    = (const float*)d_in[28];
  const float* g2     = (const float*)d_in[29];
  const float* b2n    = (const float*)d_in[30];
  const float* Wff1   = (const float*)d_in[31];
  const float* bff1   = (const float*)d_in[32];
  const float* Wff2   = (const float*)d_in[33];
  const float* bff2   = (const float*)d_in[34];
  const float* Wrp    = (const float*)d_in[35];
  const float* brp    = (const float*)d_in[36];
  const float* gbn    = (const float*)d_in[37];
  const float* bbn    = (const float*)d_in[38];

  float* ws = (float*)d_ws;
  float* RESID = ws + O_RESID;
  float* LNTM  = ws + O_LNTM;
  float* LNTR  = ws + O_LNTR;
  float* LNSM  = ws + O_LNSM;
  float* LNSR  = ws + O_LNSR;
  const size_t RSLOT  = (size_t)Bx*128*NP;   // ushorts per RA/RB slot
  const size_t S1SLOT = (size_t)Bx*64*NP;    // ushorts per S1 slot
  ushort* RAx  = (ushort*)(ws + O_XCAT);     // 3 slots
  ushort* RB0  = (ushort*)(ws + O_RB);
  ushort* RB1  = RB0 + RSLOT;                // fills O_RB region exactly
  ushort* RB2  = (ushort*)(ws + O_GACC);     // overlays dead S1 (serial: gcs128 reads S1 before agg128 writes RB2)
  ushort* S1x  = (ushort*)(ws + O_GACC);     // 3 slots
  float* Y     = ws + O_GG;
  float* XE    = ws + O_XE;
  float* BNST  = ws + O_BNST;
  ushort* WTMF = (ushort*)(ws + O_WTM);
  ushort* WTB  = (ushort*)(ws + O_WTB);
  ushort* ADJT = (ushort*)(ws + O_ADJT);
  ushort* HT   = (ushort*)(ws + O_HT);   // in dead H region
  ushort* WQ1B = (ushort*)(ws + O_WQ1B);
  ushort* WV1B = (ushort*)(ws + O_WV1B);
  ushort* WQ2B = (ushort*)(ws + O_WQ2B);
  ushort* WV2B = (ushort*)(ws + O_WV2B);
  ushort* WQT  = (ushort*)(ws + O_WQT);
  ushort* WKT  = (ushort*)(ws + O_WKT);
  ushort* WVT  = (ushort*)(ws + O_WVT);
  ushort* WFCT = (ushort*)(ws + O_WFCT);
  ushort* WF1T = (ushort*)(ws + O_WF1T);
  ushort* WF2T = (ushort*)(ws + O_WF2T);

  k_residual<<<dim3(Nn,Bx),TPB,0,stream>>>(x, Wconv1, bconv1, RESID, LNTM, LNTR);
  k_lnS<<<(Bx*Cc*Tin)/TPB,TPB,0,stream>>>(RESID, LNSM, LNSR);

  // merged converts + HT pad zero-fill (14 jobs, one dispatch)
  WJobs jobs;
  jobs.j[0]  = { wq1,  WQ1B, 64,  64,  2,  4,  64*64,   24*4*2*512, 0 };
  jobs.j[1]  = { wv1,  WV1B, 64,  64,  2,  4,  64*64,   24*4*2*512, 0 };
  jobs.j[2]  = { wq2,  WQ2B, 64,  128, 2,  8,  64*128,  24*8*2*512, 0 };
  jobs.j[3]  = { wv2,  WV2B, 64,  128, 2,  8,  64*128,  24*8*2*512, 0 };
  jobs.j[4]  = { Wq,   WQT,  64,  64,  2,  4,  64*64,   4*2*512,    0 };
  jobs.j[5]  = { Wk,   WKT,  64,  64,  2,  4,  64*64,   4*2*512,    0 };
  jobs.j[6]  = { Wv,   WVT,  64,  64,  2,  4,  64*64,   4*2*512,    0 };
  jobs.j[7]  = { Wfc,  WFCT, 512, 512, 16, 32, 512*512, 32*16*512,  0 };
  jobs.j[8]  = { Wff1, WF1T, 512, 256, 16, 16, 512*256, 16*16*512,  0 };
  jobs.j[9]  = { Wff2, WF2T, 256, 512, 8,  32, 256*512, 32*8*512,   0 };
  jobs.j[10] = { adj,  ADJT, 207, 207, 7,  13, Nn*Nn,   3*13*7*512, 0 };
  jobs.j[11] = { Wtime, WTB, 0,   0,   0,  0,  0,       8*18*512,   1 };
  jobs.j[12] = { Wmlp, WTMF, 0,   0,   0,  0,  0,       3*8*12*512, 2 };
  jobs.j[13] = { nullptr, HT, 0,  0,   0,  0,  0,       Bx*(NPa-NP)*64, 3 };
  int totalW = 2*(24*4*2*512) + 2*(24*8*2*512) + 3*(4*2*512) + 32*16*512 + 16*16*512 + 32*8*512
             + 3*13*7*512 + 8*18*512 + 3*8*12*512 + Bx*(NPa-NP)*64;
  k_wfrag_all<<<(totalW+TPB-1)/TPB,TPB,0,stream>>>(jobs);

  k_timeconv_mfma<<<dim3(Nn,Bx),TPB,0,stream>>>(RESID, LNTM, LNTR, LNSM, LNSR, gT, bT, gS, bS,
                                                WTB, btime, HT);

  // GCN chain: 3 independent layers batched; gcs128 does both d-halves per block
  k_gcs_mfma<64,0><<<dim3(169,3,Bx),TPB,0,stream>>>(HT, WQ1B, WV1B, RAx, 0, RSLOT);
  k_agg_mfma<1><<<dim3(64,Bx*3),TPB,0,stream>>>(RAx, ADJT, bias1, S1x, S1x+S1SLOT, S1x+2*S1SLOT, 64, RSLOT);
  k_gcs_mfma<128,1><<<dim3(169,3,Bx),TPB,0,stream>>>(S1x, WQ2B, WV2B, RAx, S1SLOT, RSLOT);
  k_agg_mfma<0><<<dim3(128,Bx*3),TPB,0,stream>>>(RAx, ADJT, bias2, RB0, RB1, RB2, 128, RSLOT);
  // fused MLP + patch-scramble + emb -> XE
  k_mlp_all<<<dim3(Nn,Bx),TPB,0,stream>>>(RB0, RB1, RB2, WTMF, bmlp, embT, XE);
  k_attn<<<dim3(Nn,Bx),TPA,0,stream>>>(XE, RESID, WQT,bq, WKT,bk, WVT,bv, WFCT,bfc,
                                       g1,b1n,g2,b2n, WF1T,bff1, WF2T,bff2, Wrp,brp, Y);
  k_bnstats<<<64,TPB,0,stream>>>(Y, BNST);
  k_bnout<<<(Bx*Cc*Nn*Tout)/TPB,TPB,0,stream>>>(Y, BNST, gbn, bbn, (float*)d_out);
}

// Round 28
// 737.174 us; speedup vs baseline: 1.0887x; 1.0752x over previous
//
#include <hip/hip_runtime.h>
#include <hip/hip_bf16.h>

#define TPB 256
#define TPA 512

constexpr int Bx = 8, Cc = 64, Nn = 207, Tin = 54, Kb = 8;
constexpr int LP = 52, NP = Nn * LP;     // time padded 50->52, flattened node*time positions
constexpr int NPa = 10816;               // NP rounded up to 169*64 for MFMA tiles
constexpr int L50 = 50, Tout = 48;
constexpr int Ee = 512, Pn = 12;
constexpr float EPSF = 1e-5f;
constexpr int SRDF = 516;                // padded row stride for 512-wide f32 LDS rows (2-way bank pattern)

// ---------------- workspace layout (floats) ----------------
constexpr size_t O_RESID = 0;                                   // [B][64][207][54]
constexpr size_t O_LNTM  = O_RESID + (size_t)Bx*Cc*Nn*Tin;
constexpr size_t O_LNTR  = O_LNTM  + (size_t)Bx*Cc*Nn;
constexpr size_t O_LNSM  = O_LNTR  + (size_t)Bx*Cc*Nn;          // lnS raw SUM  [Bx*Cc*Tin] (atomic)
constexpr size_t O_LNSR  = O_LNSM  + (size_t)Bx*Cc*Tin;         // lnS raw SUMSQ[Bx*Cc*Tin] (atomic)
constexpr size_t O_XCAT  = O_LNSR  + (size_t)Bx*Cc*Tin;         // RA bf16 x3 slots
constexpr size_t O_RB    = O_XCAT  + (size_t)Bx*192*Nn*Tin;     // RB0,RB1 bf16 slots
constexpr size_t O_H     = O_RB    + (size_t)Bx*128*NP;         // HT bf16 [Bx][NPa][64]
constexpr size_t O_GACC  = O_H     + (size_t)Bx*64*NP;          // S1 bf16 x3 slots; RB2 overlays dead S1
constexpr size_t O_GG    = O_GACC  + (size_t)Bx*128*Nn*Tout;    // Y [B][64][207][48]
constexpr size_t O_XE    = O_GG    + (size_t)Bx*64*Nn*Tout;     // XE [B][207][12][512]
constexpr size_t O_WTT   = O_XE    + (size_t)Bx*Nn*Pn*Ee;       // (unused)
constexpr size_t O_WTM   = O_WTT   + (size_t)128*192*3;         // ushort[3*8*12*512]
constexpr size_t O_BNST  = O_WTM   + (size_t)128*384*3;         // 128 raw sums (atomic)
constexpr size_t O_WTB   = O_BNST + 128;                        // ushort[8*18*512]
constexpr size_t O_ADJT  = O_WTB  + (size_t)128*576/2;          // ushort[3][13*7*512]
constexpr size_t O_HT    = O_H;
constexpr size_t O_WQ1B  = O_ADJT + (size_t)3*13*7*512/2;
constexpr size_t O_WV1B  = O_WQ1B + (size_t)24*4*2*512/2;
constexpr size_t O_WQ2B  = O_WV1B + (size_t)24*4*2*512/2;
constexpr size_t O_WV2B  = O_WQ2B + (size_t)24*8*2*512/2;
constexpr size_t O_WQT   = O_WV2B + (size_t)24*8*2*512/2;
constexpr size_t O_WKT   = O_WQT  + 2048;
constexpr size_t O_WVT   = O_WKT  + 2048;
constexpr size_t O_WFCT  = O_WVT  + 2048;
constexpr size_t O_WF1T  = O_WFCT + 131072;
constexpr size_t O_WF2T  = O_WF1T + 65536;

#define FMA4(acc, sA_, vB_) { (acc).x += (sA_)*(vB_).x; (acc).y += (sA_)*(vB_).y; (acc).z += (sA_)*(vB_).z; (acc).w += (sA_)*(vB_).w; }

typedef __attribute__((ext_vector_type(8))) short bf16x8;
typedef __attribute__((ext_vector_type(4))) float f32x4;

__device__ __forceinline__ float sigm(float x){ return 1.0f/(1.0f+__expf(-x)); }
__device__ __forceinline__ ushort f2bf(float x){ __hip_bfloat16 h = __float2bfloat16(x); return *(ushort*)&h; }

// ---------------- residual = W_conv1 @ x + b, fused lnT stats + lnS atomic partials ----------------
__global__ __launch_bounds__(TPB) void k_residual(const float* __restrict__ x, const float* __restrict__ W,
                                                  const float* __restrict__ bias, float* __restrict__ out,
                                                  float* __restrict__ lnm, float* __restrict__ lnr,
                                                  float* __restrict__ lnsS, float* __restrict__ lnsS2){
  int n = blockIdx.x, b = blockIdx.y;
  __shared__ __align__(16) float sX[Cc][Tin];
  __shared__ __align__(16) float sW[Cc*Cc];
  __shared__ __align__(16) float sO[Cc][Tin];
  int tid = threadIdx.x;
  for(int i=tid;i<Cc*Tin;i+=TPB){ int c=i/Tin, l=i%Tin; sX[c][l] = x[((size_t)(b*Cc+c)*Nn+n)*Tin+l]; }
  for(int i=tid;i<Cc*Cc;i+=TPB) sW[i]=W[i];
  __syncthreads();
  for(int i=tid;i<Cc*Tin;i+=TPB){
    int o=i/Tin, l=i%Tin; float acc=bias[o];
    #pragma unroll 8
    for(int c=0;c<Cc;c++) acc += sW[o*Cc+c]*sX[c][l];
    out[((size_t)(b*Cc+o)*Nn+n)*Tin+l]=acc;
    sO[o][l]=acc;
  }
  __syncthreads();
  if(tid < Cc){
    float s=0.f,s2=0.f;
    for(int l=0;l<Tin;l++){ float v=sO[tid][l]; s+=v; s2+=v*v; }
    float m=s*(1.f/Tin); float var=s2*(1.f/Tin)-m*m;
    int row = (b*Cc+tid)*Nn + n;
    lnm[row]=m; lnr[row]=rsqrtf(fmaxf(var,0.f)+EPSF);
  }
  // lnS partials: per (b,c,l) row accumulate v and v^2 across n (atomic, order-insensitive to ulps)
  for(int i=tid;i<Cc*Tin;i+=TPB){
    int c=i/Tin, l=i%Tin;
    float v = sO[c][l];
    int row = (b*Cc+c)*Tin + l;
    atomicAdd(&lnsS[row], v);
    atomicAdd(&lnsS2[row], v*v);
  }
}

// ---------------- merged converter (14 jobs: generic/timeconv/mlp/htpad-zero) ----------------
struct WJob { const float* W; ushort* F; int K, N, KS, NT, sStride, total, type; };
struct WJobs { WJob j[14]; };

__global__ __launch_bounds__(TPB) void k_wfrag_all(WJobs jobs){
  int gi = blockIdx.x*TPB + threadIdx.x;
  for(int seg=0; seg<14; seg++){
    const WJob J = jobs.j[seg];
    if(gi < J.total){
      int i = gi;
      if(J.type == 3){                        // HT pad zero-fill
        int b = i / ((NPa-NP)*64); int r = i % ((NPa-NP)*64);
        J.F[((size_t)b*NPa + NP)*64 + r] = 0;
        return;
      }
      int j = i & 7; int lane = (i>>3) & 63;
      int t = i >> 9;
      int r15 = lane & 15, hi = lane >> 4;
      float v;
      if(J.type == 0){
        int ks = t % J.KS; int r = t / J.KS; int colTile = r % J.NT; int s = r / J.NT;
        int k = ks*32 + hi*8 + j, col = colTile*16 + r15;
        v = (k < J.K && col < J.N) ? J.W[(size_t)s*J.sStride + (size_t)k*J.N + col] : 0.f;
      } else if(J.type == 1){
        int ks = t % 18; int colTile = t / 18;
        int k = ks*32 + hi*8 + j, o = colTile*16 + r15;
        int kt = k/192, ci = k - kt*192;
        v = J.W[(size_t)(o*192+ci)*3 + kt];
      } else {
        int ks = t % 12; int r = t / 12; int colTile = r & 7; int layer = r >> 3;
        int k = ks*32 + hi*8 + j;
        int kt = k >> 7, ci = k & 127;
        int o = colTile*16 + r15;
        v = J.W[(size_t)(o*384 + layer*128 + ci)*3 + kt];
      }
      J.F[i] = f2bf(v);
      return;
    }
    gi -= J.total;
  }
}

// ---------------- fused xcat+dilated time conv (dil=2) + GLU via MFMA -> HT bf16 [b][p][64] ----------------
// lnS stats computed inline from raw sums (same formula as old k_lnS)
__global__ __launch_bounds__(TPB) void k_timeconv_mfma(const float* __restrict__ resid,
    const float* __restrict__ tm, const float* __restrict__ tr,
    const float* __restrict__ lnsS, const float* __restrict__ lnsS2,
    const float* __restrict__ gT, const float* __restrict__ bT,
    const float* __restrict__ gS, const float* __restrict__ bS,
    const ushort* __restrict__ WF, const float* __restrict__ bias, ushort* __restrict__ HT){
  int n = blockIdx.x, b = blockIdx.y;
  constexpr int XS = 200;
  __shared__ __align__(16) ushort sXT[68*XS];
  int tid = threadIdx.x;
  for(int i=tid; i<14*XS; i+=TPB) sXT[54*XS + i] = 0;
  float gSn = gS[n], bSn = bS[n];
  for(int i=tid; i<64*54; i+=TPB){
    int cm = i/54, l = i%54;
    int rowT = (b*Cc+cm)*Nn + n;
    float r = resid[(size_t)rowT*Tin + l];
    float v1 = (r - tm[rowT]) * tr[rowT] * gT[l] + bT[l];
    int rowS = (b*Cc+cm)*Tin + l;
    float sm_ = lnsS[rowS]*(1.f/Nn);
    float sr_ = rsqrtf(fmaxf(lnsS2[rowS]*(1.f/Nn) - sm_*sm_, 0.f)+EPSF);
    float v2 = (r - sm_) * sr_ * gSn + bSn;
    sXT[l*XS + cm]        = f2bf(r);
    sXT[l*XS + 64 + cm]   = f2bf(v1);
    sXT[l*XS + 128 + cm]  = f2bf(v2);
  }
  __syncthreads();
  int lane = tid & 63, w = tid >> 6;
  int r15 = lane & 15, hi = lane >> 4;
  float b0 = bias[w*16 + r15], b1 = bias[w*16 + 64 + r15];
  f32x4 acc0[4], acc1[4];
  #pragma unroll
  for(int tt=0;tt<4;tt++){
    acc0[tt][0]=b0; acc0[tt][1]=b0; acc0[tt][2]=b0; acc0[tt][3]=b0;
    acc1[tt][0]=b1; acc1[tt][1]=b1; acc1[tt][2]=b1; acc1[tt][3]=b1;
  }
  const ushort* wp0 = WF + ((size_t)w*18)*512 + lane*8;
  const ushort* wp1 = WF + ((size_t)(w+4)*18)*512 + lane*8;
  #pragma unroll 2
  for(int ks=0; ks<18; ks++){
    int k0 = ks*32 + hi*8;
    int kt = k0/192, ci0 = k0 - kt*192;
    bf16x8 bw0 = *(const bf16x8*)&wp0[(size_t)ks*512];
    bf16x8 bw1 = *(const bf16x8*)&wp1[(size_t)ks*512];
    #pragma unroll
    for(int tt=0;tt<4;tt++){
      bf16x8 ax = *(const bf16x8*)&sXT[(tt*16 + r15 + 2*kt)*XS + ci0];
      acc0[tt] = __builtin_amdgcn_mfma_f32_16x16x32_bf16(ax, bw0, acc0[tt], 0,0,0);
      acc1[tt] = __builtin_amdgcn_mfma_f32_16x16x32_bf16(ax, bw1, acc1[tt], 0,0,0);
    }
  }
  ushort* htp = HT + ((size_t)b*NPa + (size_t)n*LP)*64;
  int c = w*16 + r15;
  #pragma unroll
  for(int tt=0;tt<4;tt++){
    int t0 = tt*16 + hi*4;
    #pragma unroll
    for(int i=0;i<4;i++){
      int t = t0 + i;
      if(t < L50) htp[(size_t)t*64 + c] = f2bf(tanhf(acc0[tt][i])*sigm(acc1[tt][i]));
    }
  }
  if(tid < 128){ int cz = tid >> 1, tz = 50 + (tid & 1); htp[(size_t)tz*64 + cz] = 0; }
}

// ---------------- gated multi-basis GCN einsum via MFMA; all 3 layers in one dispatch ----------------
template<int D, int TR>
__global__ __launch_bounds__(TPB) void k_gcs_mfma(const ushort* __restrict__ XT,
    const ushort* __restrict__ wqF, const ushort* __restrict__ wvF,
    ushort* __restrict__ S, size_t inSlot, size_t outSlot){
  constexpr int Dt = D/16;
  constexpr int NDH = D/64;          // d-halves processed per block
  constexpr size_t WSTR = (size_t)Kb*Dt*2*512;
  int p0 = blockIdx.x*64;
  int b = blockIdx.z;
  int iy = blockIdx.y;               // GCN layer index i in [0,3)
  int tid = threadIdx.x;
  int lane = tid & 63, w = tid >> 6;
  const ushort* wqB = wqF + iy*WSTR;
  const ushort* wvB = wvF + iy*WSTR;
  ushort* Sb = S + iy*outSlot;
  __shared__ __align__(16) ushort sX[64*64];
  if constexpr(TR){
    const ushort* Xp = XT + iy*inSlot;
    __shared__ __align__(16) ushort sT2[64*66];
    for(int i=tid;i<4096;i+=TPB){ int c=i>>6, col=i&63; int p=p0+col;
      sT2[c*66+col] = (p<NP) ? Xp[((size_t)(b*64+c))*NP + p] : (ushort)0; }
    __syncthreads();
    for(int i=tid;i<512;i+=TPB){
      int row=i>>3, c8=(i&7)<<3;
      ushort u[8];
      #pragma unroll
      for(int j=0;j<8;j++) u[j] = sT2[(c8+j)*66 + row];
      *(uint4*)&sX[row*64 + (c8 ^ ((row&7)<<3))] = *(uint4*)u;
    }
  } else {
    for(int i=tid;i<512;i+=TPB){
      int row=i>>3, c8=(i&7)<<3;
      uint4 v = *(const uint4*)&XT[((size_t)b*NPa + p0 + row)*64 + c8];
      *(uint4*)&sX[row*64 + (c8 ^ ((row&7)<<3))] = v;
    }
  }
  __syncthreads();
  int r15 = lane & 15, hi = lane >> 4;
  bf16x8 bf[4][2];
  #pragma unroll
  for(int pt=0;pt<4;pt++){
    int row = pt*16 + r15;
    int sw = (row&7)<<3;
    int cu0 = hi*8;
    bf[pt][0] = *(const bf16x8*)&sX[row*64 + (cu0 ^ sw)];
    bf[pt][1] = *(const bf16x8*)&sX[row*64 + ((cu0+32) ^ sw)];
  }
  #pragma unroll
  for(int dh=0; dh<NDH; dh++){
    int dTile = dh*4 + w;
    int d0 = dh*64 + (w<<4);
    f32x4 acc[4];
    #pragma unroll
    for(int pt=0;pt<4;pt++){ acc[pt][0]=0.f; acc[pt][1]=0.f; acc[pt][2]=0.f; acc[pt][3]=0.f; }
    const ushort* wqp = wqB + ((size_t)dTile*2)*512 + lane*8;
    const ushort* wvp = wvB + ((size_t)dTile*2)*512 + lane*8;
    for(int k=0;k<Kb;k++){
      bf16x8 aq0 = *(const bf16x8*)&wqp[0];
      bf16x8 aq1 = *(const bf16x8*)&wqp[512];
      bf16x8 av0 = *(const bf16x8*)&wvp[0];
      bf16x8 av1 = *(const bf16x8*)&wvp[512];
      wqp += (size_t)Dt*2*512; wvp += (size_t)Dt*2*512;
      #pragma unroll
      for(int pt=0;pt<4;pt++){
        f32x4 q; q[0]=0.f;q[1]=0.f;q[2]=0.f;q[3]=0.f;
        f32x4 v; v[0]=0.f;v[1]=0.f;v[2]=0.f;v[3]=0.f;
        q = __builtin_amdgcn_mfma_f32_16x16x32_bf16(aq0, bf[pt][0], q, 0,0,0);
        q = __builtin_amdgcn_mfma_f32_16x16x32_bf16(aq1, bf[pt][1], q, 0,0,0);
        v = __builtin_amdgcn_mfma_f32_16x16x32_bf16(av0, bf[pt][0], v, 0,0,0);
        v = __builtin_amdgcn_mfma_f32_16x16x32_bf16(av1, bf[pt][1], v, 0,0,0);
        #pragma unroll
        for(int i=0;i<4;i++) acc[pt][i] += v[i]*sigm(q[i]);
      }
    }
    #pragma unroll
    for(int pt=0;pt<4;pt++){
      int p = p0 + pt*16 + r15;
      if(p < NP){
        #pragma unroll
        for(int i=0;i<4;i++){
          int d = d0 + hi*4 + i;
          Sb[((size_t)b*D + d)*NP + p] = f2bf(acc[pt][i]);
        }
      }
    }
  }
}

// ---------------- adjacency aggregation via MFMA; all 3 layers in one dispatch ----------------
template<int RELU>
__global__ __launch_bounds__(TPB) void k_agg_mfma(const ushort* __restrict__ S, const ushort* __restrict__ adjF,
                                                  const float* __restrict__ bias,
                                                  ushort* __restrict__ O0, ushort* __restrict__ O1, ushort* __restrict__ O2,
                                                  int D, size_t inSlot){
  int d = blockIdx.x;
  int by = blockIdx.y;
  int b = by / 3, li = by % 3;          // li = GCN layer index
  int bd = b*D + d;
  const ushort* adjL = adjF + (size_t)li*13*7*512;
  constexpr int SST = 232;
  __shared__ __align__(16) ushort sB[64*SST];
  int tid = threadIdx.x;
  for(int i=tid*8; i<64*SST; i+=TPB*8){ uint4 z; z.x=0;z.y=0;z.z=0;z.w=0; *(uint4*)&sB[i]=z; }
  __syncthreads();
  const ushort* Sp = S + li*inSlot + (size_t)bd*NP;
  for(int i=tid; i<NP; i+=TPB){
    int nn = i/52, l = i - nn*52;
    sB[l*SST + nn] = Sp[i];
  }
  __syncthreads();
  int lane = tid & 63, w = tid >> 6;
  int r15 = lane & 15, hi = lane >> 4;
  float bb = bias[li*D + d];
  ushort* Ob = (li==0) ? O0 : (li==1 ? O1 : O2);
  ushort* Op = Ob + (size_t)bd*NP;
  for(int k2t = w; k2t < 13; k2t += 4){
    f32x4 acc[4];
    #pragma unroll
    for(int lt=0;lt<4;lt++){ acc[lt][0]=0;acc[lt][1]=0;acc[lt][2]=0;acc[lt][3]=0; }
    #pragma unroll
    for(int ks=0; ks<7; ks++){
      bf16x8 a = *(const bf16x8*)&adjL[((size_t)(k2t*7 + ks))*512 + lane*8];
      #pragma unroll
      for(int lt=0;lt<4;lt++){
        bf16x8 bfr = *(const bf16x8*)&sB[(lt*16+r15)*SST + ks*32 + hi*8];
        acc[lt] = __builtin_amdgcn_mfma_f32_16x16x32_bf16(a, bfr, acc[lt], 0,0,0);
      }
    }
    #pragma unroll
    for(int lt=0;lt<4;lt++){
      #pragma unroll
      for(int i2=0;i2<4;i2++){
        int k2 = k2t*16 + hi*4 + i2;
        int l  = lt*16 + r15;
        if(k2 < Nn && l < LP){
          float v = acc[lt][i2] + bb;
          if(RELU) v = fmaxf(v, 0.f);
          Op[(size_t)k2*LP + l] = f2bf(v);
        }
      }
    }
  }
}

// ---------------- fused MLP conv (3 layers) + patch-scramble + emb -> XE directly ----------------
__global__ __launch_bounds__(TPB) void k_mlp_all(const ushort* __restrict__ RB0, const ushort* __restrict__ RB1,
                                                 const ushort* __restrict__ RB2, const ushort* __restrict__ WF,
                                                 const float* __restrict__ bm, const float* __restrict__ emb,
                                                 float* __restrict__ xe){
  int n = blockIdx.x, b = blockIdx.y;
  constexpr int CS = 136;
  __shared__ __align__(16) ushort sLT[3*52*CS];
  int tid = threadIdx.x;
  {
    const ushort* Rp = RB0;
    for(int i=tid;i<6656;i+=TPB){ int c=i/52, l=i%52; sLT[0*52*CS + l*CS + c] = Rp[(((size_t)b*128+c)*Nn + n)*LP + l]; }
    Rp = RB1;
    for(int i=tid;i<6656;i+=TPB){ int c=i/52, l=i%52; sLT[1*52*CS + l*CS + c] = Rp[(((size_t)b*128+c)*Nn + n)*LP + l]; }
    Rp = RB2;
    for(int i=tid;i<6656;i+=TPB){ int c=i/52, l=i%52; sLT[2*52*CS + l*CS + c] = Rp[(((size_t)b*128+c)*Nn + n)*LP + l]; }
  }
  __syncthreads();
  int lane = tid & 63, w = tid >> 6;
  int r15 = lane & 15, hi = lane >> 4;
  f32x4 acc0[3], acc1[3];
  #pragma unroll
  for(int tt=0;tt<3;tt++){
    acc0[tt][0]=0;acc0[tt][1]=0;acc0[tt][2]=0;acc0[tt][3]=0;
    acc1[tt][0]=0;acc1[tt][1]=0;acc1[tt][2]=0;acc1[tt][3]=0;
  }
  #pragma unroll
  for(int layer=0; layer<3; layer++){
    const ushort* wp0 = WF + ((size_t)(layer*8 + w)*12)*512 + lane*8;
    const ushort* wp1 = WF + ((size_t)(layer*8 + w+4)*12)*512 + lane*8;
    const ushort* sL = &sLT[layer*52*CS];
    #pragma unroll 3
    for(int ks=0; ks<12; ks++){
      int kt = ks>>2, ci0 = (ks&3)*32 + hi*8;
      bf16x8 bw0 = *(const bf16x8*)&wp0[(size_t)ks*512];
      bf16x8 bw1 = *(const bf16x8*)&wp1[(size_t)ks*512];
      #pragma unroll
      for(int tt=0;tt<3;tt++){
        bf16x8 ax = *(const bf16x8*)&sL[(tt*16 + r15 + kt)*CS + ci0];
        acc0[tt] = __builtin_amdgcn_mfma_f32_16x16x32_bf16(ax, bw0, acc0[tt], 0,0,0);
        acc1[tt] = __builtin_amdgcn_mfma_f32_16x16x32_bf16(ax, bw1, acc1[tt], 0,0,0);
      }
    }
  }
  int o = w*16 + r15;
  float b0 = bm[o], b1 = bm[o+64];
  float* xeb = xe + (size_t)b*1271808;
  int off0 = o*19872 + n*96;
  #pragma unroll
  for(int tt=0;tt<3;tt++){
    #pragma unroll
    for(int i2=0;i2<4;i2++){
      int tq = tt*16 + hi*4 + i2;
      float v = tanhf(acc0[tt][i2] + b0)*sigm(acc1[tt][i2] + b1);
      int p1 = tq>>2, j1 = tq&3;
      int offa = off0 + p1*8 + j1;
      xeb[offa] = v + emb[(size_t)((offa>>9)%12)*Ee + (offa&511)];
      if(tq >= 4){
        int offb = off0 + (p1-1)*8 + j1 + 4;
        xeb[offb] = v + emb[(size_t)((offb>>9)%12)*Ee + (offb&511)];
      }
    }
  }
  {
    int o2 = tid >> 2, r2 = 92 + (tid & 3);
    int offp = o2*19872 + n*96 + r2;
    xeb[offp] = emb[(size_t)((offp>>9)%12)*Ee + (offp&511)];
  }
}

// ---------------- per-row LN helper (rows of 512, stride SRDF, in LDS); NW waves ----------------
template<int NW>
__device__ __forceinline__ void ln_rows(float* buf, const float* __restrict__ g, const float* __restrict__ be, int tid){
  int lane = tid & 63, wv = tid >> 6;
  for(int r = wv; r < 12; r += NW){
    float s=0.f, s2=0.f;
    #pragma unroll
    for(int j=0;j<8;j++){ float v = buf[r*SRDF + j*64 + lane]; s+=v; s2+=v*v; }
    #pragma unroll
    for(int off=32; off; off>>=1){ s += __shfl_xor(s,off); s2 += __shfl_xor(s2,off); }
    float m = s*(1.f/512.f);
    float rstd = rsqrtf(fmaxf(s2*(1.f/512.f)-m*m, 0.f)+EPSF);
    #pragma unroll
    for(int j=0;j<8;j++){ int e = j*64+lane; float v = buf[r*SRDF+e];
      buf[r*SRDF+e] = (v-m)*rstd*g[e] + be[e]; }
  }
}

// ---------------- fused per-(b,n) transformer, MFMA GEMM phases; 512 threads (8 waves) ----------------
__global__ __launch_bounds__(TPA,2) void k_attn(
    const float* __restrict__ xe, const float* __restrict__ resid,
    const ushort* __restrict__ WqF, const float* __restrict__ bq,
    const ushort* __restrict__ WkF, const float* __restrict__ bk,
    const ushort* __restrict__ WvF, const float* __restrict__ bv,
    const ushort* __restrict__ WfcF, const float* __restrict__ bfc,
    const float* __restrict__ g1, const float* __restrict__ b1n,
    const float* __restrict__ g2, const float* __restrict__ b2n,
    const ushort* __restrict__ Wff1F, const float* __restrict__ bff1,
    const ushort* __restrict__ Wff2F, const float* __restrict__ bff2,
    const float* __restrict__ Wrp, const float* __restrict__ brp,
    float* __restrict__ y)
{
  int n = blockIdx.x, b = blockIdx.y;
  __shared__ __align__(16) ushort SbX[16*512];
  __shared__ __align__(16) ushort Mb[16*256];
  __shared__ __align__(16) float U0[12*SRDF];
  __shared__ __align__(16) float U1[12*SRDF];
  __shared__ __align__(16) float sS[1160];
  int tid = threadIdx.x;
  int lane = tid & 63, w = tid >> 6;          // w in [0,8)
  int r15 = lane & 15, hi = lane >> 4;
  const float* __restrict__ xeg = xe + ((size_t)b*Nn + n)*6144;

  for(int i=tid;i<1024;i+=TPA){
    int r = i>>6, ch = i&63;
    ushort u[8];
    if(r<12){
      const float* s = &xeg[r*512 + ch*8];
      #pragma unroll
      for(int j=0;j<8;j++) u[j] = f2bf(s[j]);
    } else {
      #pragma unroll
      for(int j=0;j<8;j++) u[j] = 0;
    }
    *(uint4*)&SbX[r*512 + ((ch ^ (r&7))<<3)] = *(uint4*)u;
  }
  for(int i=tid;i<128;i+=TPA){
    int r = 12 + (i>>5), ch = i&31;
    uint4 z; z.x=0;z.y=0;z.z=0;z.w=0;
    *(uint4*)&Mb[r*256 + ch*8] = z;
  }
  __syncthreads();

  // QKV: one head per wave
  f32x4 vfrag[4];
  {
    int head = w;
    bf16x8 a0, a1;
    { int ch0 = head*8 + hi, ch1 = head*8 + 4 + hi;
      a0 = *(const bf16x8*)&SbX[r15*512 + ((ch0 ^ (r15&7))<<3)];
      a1 = *(const bf16x8*)&SbX[r15*512 + ((ch1 ^ (r15&7))<<3)]; }
    #pragma unroll
    for(int nt=0;nt<4;nt++){
      int col = nt*16 + r15;
      float bb = bq[col];
      f32x4 acc; acc[0]=bb;acc[1]=bb;acc[2]=bb;acc[3]=bb;
      acc = __builtin_amdgcn_mfma_f32_16x16x32_bf16(a0, *(const bf16x8*)&WqF[(size_t)(nt*2+0)*512 + lane*8], acc, 0,0,0);
      acc = __builtin_amdgcn_mfma_f32_16x16x32_bf16(a1, *(const bf16x8*)&WqF[(size_t)(nt*2+1)*512 + lane*8], acc, 0,0,0);
      #pragma unroll
      for(int i2=0;i2<4;i2++){ int p = hi*4+i2; if(p<12) U0[p*SRDF + head*64 + col] = acc[i2]; }
    }
    #pragma unroll
    for(int nt=0;nt<4;nt++){
      int col = nt*16 + r15;
      float bb = bk[col];
      f32x4 acc; acc[0]=bb;acc[1]=bb;acc[2]=bb;acc[3]=bb;
      acc = __builtin_amdgcn_mfma_f32_16x16x32_bf16(a0, *(const bf16x8*)&WkF[(size_t)(nt*2+0)*512 + lane*8], acc, 0,0,0);
      acc = __builtin_amdgcn_mfma_f32_16x16x32_bf16(a1, *(const bf16x8*)&WkF[(size_t)(nt*2+1)*512 + lane*8], acc, 0,0,0);
      #pragma unroll
      for(int i2=0;i2<4;i2++){ int p = hi*4+i2; if(p<12) U1[p*SRDF + head*64 + col] = acc[i2]; }
    }
    #pragma unroll
    for(int nt=0;nt<4;nt++){
      int col = nt*16 + r15;
      float bb = bv[col];
      f32x4 acc; acc[0]=bb;acc[1]=bb;acc[2]=bb;acc[3]=bb;
      acc = __builtin_amdgcn_mfma_f32_16x16x32_bf16(a0, *(const bf16x8*)&WvF[(size_t)(nt*2+0)*512 + lane*8], acc, 0,0,0);
      acc = __builtin_amdgcn_mfma_f32_16x16x32_bf16(a1, *(const bf16x8*)&WvF[(size_t)(nt*2+1)*512 + lane*8], acc, 0,0,0);
      vfrag[nt] = acc;
    }
  }
  __syncthreads();

  const float scale = 0.04419417382415922f;   // 1/sqrt(512)
  for(int i=tid;i<1152;i+=TPA){
    int q = i%12, kh = i/12; int h2 = kh&7, k2 = kh>>3;
    const float* qp = &U0[q*SRDF + h2*64];
    const float* kp = &U1[k2*SRDF + h2*64];
    float s=0.f;
    #pragma unroll
    for(int d4=0; d4<16; d4++){
      float4 a4 = *(const float4*)&qp[d4*4];
      float4 b4 = *(const float4*)&kp[d4*4];
      s += a4.x*b4.x + a4.y*b4.y + a4.z*b4.z + a4.w*b4.w;
    }
    sS[i] = s*scale;
  }
  __syncthreads();
  {
    int head = w;
    #pragma unroll
    for(int nt=0;nt<4;nt++){
      int col = nt*16 + r15;
      #pragma unroll
      for(int i2=0;i2<4;i2++){ int p = hi*4+i2; if(p<12) U0[p*SRDF + head*64 + col] = vfrag[nt][i2]; }
    }
  }
  if(tid<96){
    float mx=-1e30f;
    for(int q=0;q<12;q++) mx = fmaxf(mx, sS[tid*12+q]);
    float sm=0.f;
    for(int q=0;q<12;q++){ float e = __expf(sS[tid*12+q]-mx); sS[tid*12+q]=e; sm+=e; }
    float inv = 1.f/sm;
    for(int q=0;q<12;q++) sS[tid*12+q] *= inv;
  }
  __syncthreads();

  for(int i=tid;i<6144;i+=TPA){
    int q=i>>9, h2=(i>>6)&7, d=i&63;
    float s=0.f;
    #pragma unroll
    for(int k2=0;k2<12;k2++) s += sS[(k2*8+h2)*12+q]*U0[k2*SRDF+h2*64+d];
    int kk = i & 511;
    SbX[q*512 + (((kk>>3) ^ (q&7))<<3) + (kk&7)] = f2bf(s);
  }
  __syncthreads();

  // fc: 32 col-tiles, 4 per wave
  {
    f32x4 acc[4];
    #pragma unroll
    for(int nt=0;nt<4;nt++){ float bb = bfc[(w*4+nt)*16 + r15]; acc[nt][0]=bb;acc[nt][1]=bb;acc[nt][2]=bb;acc[nt][3]=bb; }
    for(int ks=0;ks<16;ks++){
      int ch = ks*4 + hi;
      bf16x8 a = *(const bf16x8*)&SbX[r15*512 + ((ch ^ (r15&7))<<3)];
      #pragma unroll
      for(int nt=0;nt<4;nt++){
        acc[nt] = __builtin_amdgcn_mfma_f32_16x16x32_bf16(a, *(const bf16x8*)&WfcF[(size_t)((w*4+nt)*16 + ks)*512 + lane*8], acc[nt], 0,0,0);
      }
    }
    #pragma unroll
    for(int nt=0;nt<4;nt++){
      int col = (w*4+nt)*16 + r15;
      #pragma unroll
      for(int i2=0;i2<4;i2++){ int p = hi*4+i2; if(p<12) U1[p*SRDF + col] = acc[nt][i2] + xeg[p*512 + col]; }
    }
  }
  __syncthreads();
  ln_rows<8>(U1, g1, b1n, tid);     // M in U1
  __syncthreads();

  for(int i=tid;i<6144;i+=TPA){
    int r=i>>9, kk=i&511;
    SbX[r*512 + (((kk>>3) ^ (r&7))<<3) + (kk&7)] = f2bf(U1[r*SRDF + kk]);
  }
  __syncthreads();

  // ff1: 16 col-tiles, 2 per wave
  {
    f32x4 acc[2];
    #pragma unroll
    for(int nt=0;nt<2;nt++){ float bb = bff1[(w*2+nt)*16 + r15]; acc[nt][0]=bb;acc[nt][1]=bb;acc[nt][2]=bb;acc[nt][3]=bb; }
    for(int ks=0;ks<16;ks++){
      int ch = ks*4 + hi;
      bf16x8 a = *(const bf16x8*)&SbX[r15*512 + ((ch ^ (r15&7))<<3)];
      #pragma unroll
      for(int nt=0;nt<2;nt++){
        acc[nt] = __builtin_amdgcn_mfma_f32_16x16x32_bf16(a, *(const bf16x8*)&Wff1F[(size_t)((w*2+nt)*16 + ks)*512 + lane*8], acc[nt], 0,0,0);
      }
    }
    #pragma unroll
    for(int nt=0;nt<2;nt++){
      int u = (w*2+nt)*16 + r15;
      #pragma unroll
      for(int i2=0;i2<4;i2++){
        int p = hi*4+i2;
        if(p<12) Mb[p*256 + (((u>>3) ^ (p&7))<<3) + (u&7)] = f2bf(fmaxf(acc[nt][i2], 0.f));
      }
    }
  }
  __syncthreads();

  // ff2: 32 col-tiles, 4 per wave
  {
    f32x4 acc[4];
    #pragma unroll
    for(int nt=0;nt<4;nt++){ float bb = bff2[(w*4+nt)*16 + r15]; acc[nt][0]=bb;acc[nt][1]=bb;acc[nt][2]=bb;acc[nt][3]=bb; }
    for(int ks=0;ks<8;ks++){
      int ch = ks*4 + hi;
      bf16x8 a = *(const bf16x8*)&Mb[r15*256 + ((ch ^ (r15&7))<<3)];
      #pragma unroll
      for(int nt=0;nt<4;nt++){
        acc[nt] = __builtin_amdgcn_mfma_f32_16x16x32_bf16(a, *(const bf16x8*)&Wff2F[(size_t)((w*4+nt)*8 + ks)*512 + lane*8], acc[nt], 0,0,0);
      }
    }
    #pragma unroll
    for(int nt=0;nt<4;nt++){
      int col = (w*4+nt)*16 + r15;
      #pragma unroll
      for(int i2=0;i2<4;i2++){ int p = hi*4+i2; if(p<12) U0[p*SRDF + col] = acc[nt][i2] + U1[p*SRDF + col]; }
    }
  }
  __syncthreads();
  ln_rows<8>(U0, g2, b2n, tid);     // U in U0
  __syncthreads();

  for(int i=tid;i<6144;i+=TPA){
    int r=i>>9, c=i&511;
    U1[r*SRDF+c] = U0[r*SRDF+c] + U1[r*SRDF+c] + xeg[r*512+c];
  }
  __syncthreads();
  for(int i=tid;i<4608;i+=TPA) U0[i] = Wrp[i];
  __syncthreads();
  #pragma unroll
  for(int j=0;j<2;j++){
    int i4 = tid + j*TPA;
    if(i4 < 768){
      int c = i4/12, tq = i4%12; int t0 = tq*4;
      float4 acc = *(const float4*)&brp[t0];
      for(int t96=0;t96<96;t96++){
        int f = c*96 + t96;
        float a = U1[(f>>9)*SRDF + (f&511)];
        float4 w4 = *(const float4*)&U0[t96*48 + t0];
        FMA4(acc, a, w4);
      }
      size_t rb = (((size_t)b*Cc+c)*Nn + n)*Tin + 6 + t0;
      acc.x += resid[rb+0]; acc.y += resid[rb+1]; acc.z += resid[rb+2]; acc.w += resid[rb+3];
      *(float4*)&y[(((size_t)b*Cc+c)*Nn + n)*Tout + t0] = acc;
    }
  }
}

// ---------------- batchnorm: widened partial stats via atomics ----------------
__global__ __launch_bounds__(TPB) void k_bnstats(const float* __restrict__ y, float* __restrict__ stats){
  int c = blockIdx.x; int chunk = blockIdx.y; int tid = threadIdx.x;
  const int per = Nn*Tout;   // 9936
  const int total = Bx*per;  // 79488
  const int CH = total/16;   // 4968
  float s=0.f,s2=0.f;
  for(int idx=chunk*CH+tid; idx<chunk*CH+CH; idx+=TPB){
    int b = idx/per, r = idx%per;
    float v = y[((size_t)b*Cc+c)*per + r];
    s+=v; s2+=v*v;
  }
  __shared__ float rs[TPB], rs2[TPB];
  rs[tid]=s; rs2[tid]=s2; __syncthreads();
  for(int off=TPB/2; off; off>>=1){ if(tid<off){ rs[tid]+=rs[tid+off]; rs2[tid]+=rs2[tid+off]; } __syncthreads(); }
  if(tid==0){
    atomicAdd(&stats[c], rs[0]);
    atomicAdd(&stats[64+c], rs2[0]);
  }
}
__global__ __launch_bounds__(TPB) void k_bnout(const float* __restrict__ y, const float* __restrict__ stats,
                                               const float* __restrict__ gbn, const float* __restrict__ bbn,
                                               float* __restrict__ out){
  size_t i = (size_t)blockIdx.x*TPB + threadIdx.x;
  if(i >= (size_t)Bx*Cc*Nn*Tout) return;
  int c = (int)((i/(Nn*Tout))%Cc);
  const float cnt = (float)(Bx*Nn*Tout);
  float m = stats[c]/cnt;
  float var = stats[64+c]/cnt - m*m;
  float rstd = rsqrtf(fmaxf(var,0.f)+EPSF);
  out[i] = (y[i]-m)*rstd*gbn[c] + bbn[c];
}

// ---------------- launch ----------------
extern "C" void kernel_launch(void* const* d_in, const int* in_sizes, int n_in,
                              void* d_out, int out_size, void* d_ws, size_t ws_size,
                              hipStream_t stream) {
  const float* x      = (const float*)d_in[0];
  const float* adj    = (const float*)d_in[1];
  const float* Wconv1 = (const float*)d_in[2];
  const float* bconv1 = (const float*)d_in[3];
  const float* gT     = (const float*)d_in[4];
  const float* bT     = (const float*)d_in[5];
  const float* gS     = (const float*)d_in[6];
  const float* bS     = (const float*)d_in[7];
  const float* Wtime  = (const float*)d_in[8];
  const float* btime  = (const float*)d_in[9];
  const float* wq1    = (const float*)d_in[10];
  const float* wv1    = (const float*)d_in[11];
  const float* bias1  = (const float*)d_in[12];
  const float* wq2    = (const float*)d_in[13];
  const float* wv2    = (const float*)d_in[14];
  const float* bias2  = (const float*)d_in[15];
  const float* Wmlp   = (const float*)d_in[16];
  const float* bmlp   = (const float*)d_in[17];
  const float* embT   = (const float*)d_in[18];
  const float* Wq     = (const float*)d_in[19];
  const float* bq     = (const float*)d_in[20];
  const float* Wk     = (const float*)d_in[21];
  const float* bk     = (const float*)d_in[22];
  const float* Wv     = (const float*)d_in[23];
  const float* bv     = (const float*)d_in[24];
  const float* Wfc    = (const float*)d_in[25];
  const float* bfc    = (const float*)d_in[26];
  const float* g1     = (const float*)d_in[27];
  const float* b1n    = (const float*)d_in[28];
  const float* g2     = (const float*)d_in[29];
  const float* b2n    = (const float*)d_in[30];
  const float* Wff1   = (const float*)d_in[31];
  const float* bff1   = (const float*)d_in[32];
  const float* Wff2   = (const float*)d_in[33];
  const float* bff2   = (const float*)d_in[34];
  const float* Wrp    = (const float*)d_in[35];
  const float* brp    = (const float*)d_in[36];
  const float* gbn    = (const float*)d_in[37];
  const float* bbn    = (const float*)d_in[38];

  float* ws = (float*)d_ws;
  float* RESID = ws + O_RESID;
  float* LNTM  = ws + O_LNTM;
  float* LNTR  = ws + O_LNTR;
  float* LNSS  = ws + O_LNSM;   // raw sum
  float* LNSS2 = ws + O_LNSR;   // raw sumsq
  const size_t RSLOT  = (size_t)Bx*128*NP;   // ushorts per RA/RB slot
  const size_t S1SLOT = (size_t)Bx*64*NP;    // ushorts per S1 slot
  ushort* RAx  = (ushort*)(ws + O_XCAT);     // 3 slots
  ushort* RB0  = (ushort*)(ws + O_RB);
  ushort* RB1  = RB0 + RSLOT;
  ushort* RB2  = (ushort*)(ws + O_GACC);     // overlays dead S1
  ushort* S1x  = (ushort*)(ws + O_GACC);     // 3 slots
  float* Y     = ws + O_GG;
  float* XE    = ws + O_XE;
  float* BNST  = ws + O_BNST;
  ushort* WTMF = (ushort*)(ws + O_WTM);
  ushort* WTB  = (ushort*)(ws + O_WTB);
  ushort* ADJT = (ushort*)(ws + O_ADJT);
  ushort* HT   = (ushort*)(ws + O_HT);
  ushort* WQ1B = (ushort*)(ws + O_WQ1B);
  ushort* WV1B = (ushort*)(ws + O_WV1B);
  ushort* WQ2B = (ushort*)(ws + O_WQ2B);
  ushort* WV2B = (ushort*)(ws + O_WV2B);
  ushort* WQT  = (ushort*)(ws + O_WQT);
  ushort* WKT  = (ushort*)(ws + O_WKT);
  ushort* WVT  = (ushort*)(ws + O_WVT);
  ushort* WFCT = (ushort*)(ws + O_WFCT);
  ushort* WF1T = (ushort*)(ws + O_WF1T);
  ushort* WF2T = (ushort*)(ws + O_WF2T);

  // zero atomic-accumulator buffers (capture-legal async ops)
  hipMemsetAsync(LNSS, 0, (size_t)2*Bx*Cc*Tin*sizeof(float), stream);   // covers LNSS + LNSS2 (adjacent)
  hipMemsetAsync(BNST, 0, 128*sizeof(float), stream);

  k_residual<<<dim3(Nn,Bx),TPB,0,stream>>>(x, Wconv1, bconv1, RESID, LNTM, LNTR, LNSS, LNSS2);

  // merged converts + HT pad zero-fill (14 jobs, one dispatch)
  WJobs jobs;
  jobs.j[0]  = { wq1,  WQ1B, 64,  64,  2,  4,  64*64,   24*4*2*512, 0 };
  jobs.j[1]  = { wv1,  WV1B, 64,  64,  2,  4,  64*64,   24*4*2*512, 0 };
  jobs.j[2]  = { wq2,  WQ2B, 64,  128, 2,  8,  64*128,  24*8*2*512, 0 };
  jobs.j[3]  = { wv2,  WV2B, 64,  128, 2,  8,  64*128,  24*8*2*512, 0 };
  jobs.j[4]  = { Wq,   WQT,  64,  64,  2,  4,  64*64,   4*2*512,    0 };
  jobs.j[5]  = { Wk,   WKT,  64,  64,  2,  4,  64*64,   4*2*512,    0 };
  jobs.j[6]  = { Wv,   WVT,  64,  64,  2,  4,  64*64,   4*2*512,    0 };
  jobs.j[7]  = { Wfc,  WFCT, 512, 512, 16, 32, 512*512, 32*16*512,  0 };
  jobs.j[8]  = { Wff1, WF1T, 512, 256, 16, 16, 512*256, 16*16*512,  0 };
  jobs.j[9]  = { Wff2, WF2T, 256, 512, 8,  32, 256*512, 32*8*512,   0 };
  jobs.j[10] = { adj,  ADJT, 207, 207, 7,  13, Nn*Nn,   3*13*7*512, 0 };
  jobs.j[11] = { Wtime, WTB, 0,   0,   0,  0,  0,       8*18*512,   1 };
  jobs.j[12] = { Wmlp, WTMF, 0,   0,   0,  0,  0,       3*8*12*512, 2 };
  jobs.j[13] = { nullptr, HT, 0,  0,   0,  0,  0,       Bx*(NPa-NP)*64, 3 };
  int totalW = 2*(24*4*2*512) + 2*(24*8*2*512) + 3*(4*2*512) + 32*16*512 + 16*16*512 + 32*8*512
             + 3*13*7*512 + 8*18*512 + 3*8*12*512 + Bx*(NPa-NP)*64;
  k_wfrag_all<<<(totalW+TPB-1)/TPB,TPB,0,stream>>>(jobs);

  k_timeconv_mfma<<<dim3(Nn,Bx),TPB,0,stream>>>(RESID, LNTM, LNTR, LNSS, LNSS2, gT, bT, gS, bS,
                                                WTB, btime, HT);

  // GCN chain: 3 independent layers batched; gcs128 does both d-halves per block
  k_gcs_mfma<64,0><<<dim3(169,3,Bx),TPB,0,stream>>>(HT, WQ1B, WV1B, RAx, 0, RSLOT);
  k_agg_mfma<1><<<dim3(64,Bx*3),TPB,0,stream>>>(RAx, ADJT, bias1, S1x, S1x+S1SLOT, S1x+2*S1SLOT, 64, RSLOT);
  k_gcs_mfma<128,1><<<dim3(169,3,Bx),TPB,0,stream>>>(S1x, WQ2B, WV2B, RAx, S1SLOT, RSLOT);
  k_agg_mfma<0><<<dim3(128,Bx*3),TPB,0,stream>>>(RAx, ADJT, bias2, RB0, RB1, RB2, 128, RSLOT);
  // fused MLP + patch-scramble + emb -> XE
  k_mlp_all<<<dim3(Nn,Bx),TPB,0,stream>>>(RB0, RB1, RB2, WTMF, bmlp, embT, XE);
  k_attn<<<dim3(Nn,Bx),TPA,0,stream>>>(XE, RESID, WQT,bq, WKT,bk, WVT,bv, WFCT,bfc,
                                       g1,b1n,g2,b2n, WF1T,bff1, WF2T,bff2, Wrp,brp, Y);
  k_bnstats<<<dim3(64,16),TPB,0,stream>>>(Y, BNST);
  k_bnout<<<(Bx*Cc*Nn*Tout)/TPB,TPB,0,stream>>>(Y, BNST, gbn, bbn, (float*)d_out);
}